// Round 1
// baseline (2067.803 us; speedup 1.0000x reference)
//
#include <hip/hip_runtime.h>
#include <hip/hip_bf16.h>
#include <math.h>

#define NB 512

// ---------------- conv1: [B,1,4096] -> conv(k5,pad2)+relu+maxpool2 -> [B,16,2048]
__global__ __launch_bounds__(256) void conv1_pool(const float* __restrict__ x,
                                                  const float* __restrict__ w,
                                                  const float* __restrict__ bias,
                                                  float* __restrict__ out) {
    int idx = blockIdx.x * 256 + threadIdx.x;          // B*16*2048
    int lp = idx & 2047;
    int c  = (idx >> 11) & 15;
    int b  = idx >> 15;
    const float* xb = x + b * 4096;
    float wv[5];
#pragma unroll
    for (int k = 0; k < 5; ++k) wv[k] = w[c * 5 + k];
    float bv = bias[c];
    int l0 = 2 * lp;
    float v0 = bv, v1 = bv;
    if (l0 >= 2 && l0 + 3 < 4096) {
        const float* s = xb + l0 - 2;
        float s0 = s[0], s1 = s[1], s2 = s[2], s3 = s[3], s4 = s[4], s5 = s[5];
        v0 = fmaf(wv[0], s0, fmaf(wv[1], s1, fmaf(wv[2], s2, fmaf(wv[3], s3, fmaf(wv[4], s4, v0)))));
        v1 = fmaf(wv[0], s1, fmaf(wv[1], s2, fmaf(wv[2], s3, fmaf(wv[3], s4, fmaf(wv[4], s5, v1)))));
    } else {
#pragma unroll
        for (int k = 0; k < 5; ++k) {
            int i0 = l0 + k - 2;
            float xv0 = (i0 >= 0 && i0 < 4096) ? xb[i0] : 0.f;
            int i1 = i0 + 1;
            float xv1 = (i1 >= 0 && i1 < 4096) ? xb[i1] : 0.f;
            v0 = fmaf(wv[k], xv0, v0);
            v1 = fmaf(wv[k], xv1, v1);
        }
    }
    out[idx] = fmaxf(fmaxf(v0, v1), 0.f);
}

// ---------------- conv2: [B,16,2048] -> conv(k5,pad2)+relu+maxpool2 -> [B,32,1024]
__global__ __launch_bounds__(256) void conv2_pool(const float* __restrict__ h1,
                                                  const float* __restrict__ w,
                                                  const float* __restrict__ bias,
                                                  float* __restrict__ out) {
    int idx = blockIdx.x * 256 + threadIdx.x;          // B*32*1024
    int lp = idx & 1023;
    int c2 = (idx >> 10) & 31;
    int b  = idx >> 15;
    const float* hb = h1 + b * 16 * 2048;
    int l0 = 2 * lp;
    float v0 = bias[c2], v1 = v0;
    bool interior = (l0 >= 2) && (l0 + 3 < 2048);
    if (interior) {
        for (int c1 = 0; c1 < 16; ++c1) {
            const float* src = hb + c1 * 2048 + l0 - 2;
            const float* wr = w + (c2 * 16 + c1) * 5;
            float w0 = wr[0], w1 = wr[1], w2 = wr[2], w3 = wr[3], w4 = wr[4];
            float s0 = src[0], s1 = src[1], s2 = src[2], s3 = src[3], s4 = src[4], s5 = src[5];
            v0 = fmaf(w0, s0, fmaf(w1, s1, fmaf(w2, s2, fmaf(w3, s3, fmaf(w4, s4, v0)))));
            v1 = fmaf(w0, s1, fmaf(w1, s2, fmaf(w2, s3, fmaf(w3, s4, fmaf(w4, s5, v1)))));
        }
    } else {
        for (int c1 = 0; c1 < 16; ++c1) {
            const float* src = hb + c1 * 2048;
            const float* wr = w + (c2 * 16 + c1) * 5;
#pragma unroll
            for (int k = 0; k < 5; ++k) {
                int i0 = l0 + k - 2;
                float xv0 = (i0 >= 0 && i0 < 2048) ? src[i0] : 0.f;
                int i1 = i0 + 1;
                float xv1 = (i1 >= 0 && i1 < 2048) ? src[i1] : 0.f;
                v0 = fmaf(wr[k], xv0, v0);
                v1 = fmaf(wr[k], xv1, v1);
            }
        }
    }
    out[idx] = fmaxf(fmaxf(v0, v1), 0.f);
}

// ---------------- conv3 + relu + adaptive avg pool(32): [B,32,1024] -> [B,64,32] flat [B,2048]
__global__ __launch_bounds__(256) void conv3_pool(const float* __restrict__ h2,
                                                  const float* __restrict__ w,
                                                  const float* __restrict__ bias,
                                                  float* __restrict__ h3) {
    int idx = blockIdx.x * 256 + threadIdx.x;          // B*64*32
    int wi = idx & 31;
    int c3 = (idx >> 5) & 63;
    int b  = idx >> 11;
    int base = wi * 32;
    float bv = bias[c3];
    float v[32];
#pragma unroll
    for (int j = 0; j < 32; ++j) v[j] = bv;
    bool interior = (wi >= 1) && (wi <= 30);
    for (int c1 = 0; c1 < 32; ++c1) {
        const float* src = h2 + (b * 32 + c1) * 1024 + base;
        const float* wr = w + (c3 * 32 + c1) * 5;
        float w0 = wr[0], w1 = wr[1], w2 = wr[2], w3 = wr[3], w4 = wr[4];
        float s[36];
        if (interior) {
#pragma unroll
            for (int t = 0; t < 36; ++t) s[t] = src[t - 2];
        } else {
#pragma unroll
            for (int t = 0; t < 36; ++t) {
                int li = base + t - 2;
                s[t] = (li >= 0 && li < 1024) ? src[t - 2] : 0.f;
            }
        }
#pragma unroll
        for (int j = 0; j < 32; ++j) {
            v[j] = fmaf(w0, s[j], fmaf(w1, s[j + 1], fmaf(w2, s[j + 2],
                    fmaf(w3, s[j + 3], fmaf(w4, s[j + 4], v[j])))));
        }
    }
    float acc = 0.f;
#pragma unroll
    for (int j = 0; j < 32; ++j) acc += fmaxf(v[j], 0.f);
    h3[idx] = acc * (1.f / 32.f);
}

// ---------------- GEMM: C[512,4096] = h3[512,2048] @ lw[4096,2048]^T + lb
__global__ __launch_bounds__(256) void lin_gemm(const float* __restrict__ A,
                                                const float* __restrict__ Bw,
                                                const float* __restrict__ bias,
                                                float* __restrict__ C) {
    __shared__ float As[16][68];
    __shared__ float Bs[16][68];
    int t  = threadIdx.x;
    int tx = t & 15, ty = t >> 4;
    int row0 = blockIdx.y * 64;
    int col0 = blockIdx.x * 64;
    float acc[4][4] = {};
    for (int k0 = 0; k0 < 2048; k0 += 16) {
        for (int i = t; i < 64 * 16; i += 256) {
            int r = i >> 4, c = i & 15;
            As[c][r] = A[(row0 + r) * 2048 + k0 + c];
            Bs[c][r] = Bw[(col0 + r) * 2048 + k0 + c];
        }
        __syncthreads();
#pragma unroll
        for (int kk = 0; kk < 16; ++kk) {
            float a[4], bv[4];
#pragma unroll
            for (int i = 0; i < 4; ++i) a[i] = As[kk][ty * 4 + i];
#pragma unroll
            for (int j = 0; j < 4; ++j) bv[j] = Bs[kk][tx * 4 + j];
#pragma unroll
            for (int i = 0; i < 4; ++i)
#pragma unroll
                for (int j = 0; j < 4; ++j)
                    acc[i][j] = fmaf(a[i], bv[j], acc[i][j]);
        }
        __syncthreads();
    }
    int rbase = row0 + ty * 4, cbase = col0 + tx * 4;
#pragma unroll
    for (int i = 0; i < 4; ++i)
#pragma unroll
        for (int j = 0; j < 4; ++j)
            C[(rbase + i) * 4096 + cbase + j] = acc[i][j] + bias[cbase + j];
}

// ---------------- fused double {layernorm + mamba}: [B,64,64] -> [B,64,64]
struct MambaP {
    const float *lng, *lnb, *inw, *cvw, *cvb, *xpw, *dtw, *dtb, *al, *dp, *ow;
};

__global__ __launch_bounds__(256) void mamba2_kernel(const float* __restrict__ lin,
                                                     MambaP p1, MambaP p2,
                                                     float* __restrict__ out) {
    __shared__ float X[64][65];    // input -> xln -> z -> out1
    __shared__ float XI[64][65];   // xi -> u (in place)
    __shared__ float Yb[64][65];   // y before out-proj
    __shared__ float dtr[64][4], Bm[64][4], Cm[64][4];
    int b = blockIdx.x, t = threadIdx.x;

    for (int i = t; i < 4096; i += 256) X[i >> 6][i & 63] = lin[b * 4096 + i];
    __syncthreads();

    for (int blk = 0; blk < 2; ++blk) {
        MambaP P = blk ? p2 : p1;

        // ---- LayerNorm over d (in place), one thread per row l
        if (t < 64) {
            int l = t;
            float m = 0.f;
#pragma unroll
            for (int d = 0; d < 64; ++d) m += X[l][d];
            m *= (1.f / 64.f);
            float v = 0.f;
#pragma unroll
            for (int d = 0; d < 64; ++d) { float df = X[l][d] - m; v = fmaf(df, df, v); }
            v *= (1.f / 64.f);
            float rstd = rsqrtf(v + 1e-5f);
#pragma unroll
            for (int d = 0; d < 64; ++d)
                X[l][d] = (X[l][d] - m) * rstd * P.lng[d] + P.lnb[d];
        }
        __syncthreads();

        // ---- in-projection: xz[l][e] = dot(X[l], inw[e]); e<64 -> XI, e>=64 -> z (regs, then into X)
        {
            int e = t & 127, half = t >> 7;
            const float4* w4 = (const float4*)(P.inw + e * 64);
            float zreg[32];
#pragma unroll 4
            for (int i = 0; i < 32; ++i) {
                int l = half * 32 + i;
                float acc0 = 0.f, acc1 = 0.f;
#pragma unroll
                for (int k4 = 0; k4 < 16; ++k4) {
                    float4 wv = w4[k4];
                    int k = k4 * 4;
                    acc0 = fmaf(X[l][k], wv.x, acc0);
                    acc1 = fmaf(X[l][k + 1], wv.y, acc1);
                    acc0 = fmaf(X[l][k + 2], wv.z, acc0);
                    acc1 = fmaf(X[l][k + 3], wv.w, acc1);
                }
                float acc = acc0 + acc1;
                if (e < 64) XI[l][e] = acc; else zreg[i] = acc;
            }
            __syncthreads();
            if (e >= 64) {
                int d = e - 64;
#pragma unroll 4
                for (int i = 0; i < 32; ++i) X[half * 32 + i][d] = zreg[i];
            }
        }
        __syncthreads();

        // ---- causal depthwise conv(k=2) + silu, in place on XI; one thread per channel d
        if (t < 64) {
            int d = t;
            float w0 = P.cvw[d * 2], w1 = P.cvw[d * 2 + 1], cb = P.cvb[d];
            float prev = 0.f;
            for (int l = 0; l < 64; ++l) {
                float cur = XI[l][d];
                float v = fmaf(w0, prev, fmaf(w1, cur, cb));
                XI[l][d] = v / (1.f + __expf(-v));
                prev = cur;
            }
        }
        __syncthreads();

        // ---- x_dbl = u @ xpw^T : 12 outputs per row l
        {
            int l = t & 63, jg = t >> 6;
#pragma unroll
            for (int jj = 0; jj < 3; ++jj) {
                int j = jg * 3 + jj;
                const float* xr = P.xpw + j * 64;
                float acc0 = 0.f, acc1 = 0.f;
#pragma unroll
                for (int k = 0; k < 64; k += 2) {
                    acc0 = fmaf(XI[l][k], xr[k], acc0);
                    acc1 = fmaf(XI[l][k + 1], xr[k + 1], acc1);
                }
                float acc = acc0 + acc1;
                if (j < 4) dtr[l][j] = acc;
                else if (j < 8) Bm[l][j - 4] = acc;
                else Cm[l][j - 8] = acc;
            }
        }
        __syncthreads();

        // ---- selective scan: thread = (d = t>>2, n = t&3)
        {
            int d = t >> 2, n = t & 3;
            float Aval = -__expf(P.al[d * 4 + n]);
            float dw0 = P.dtw[d * 4], dw1 = P.dtw[d * 4 + 1], dw2 = P.dtw[d * 4 + 2], dw3 = P.dtw[d * 4 + 3];
            float db = P.dtb[d], dpv = P.dp[d];
            float h = 0.f;
            for (int l = 0; l < 64; ++l) {
                float dtv = fmaf(dw0, dtr[l][0], fmaf(dw1, dtr[l][1],
                            fmaf(dw2, dtr[l][2], fmaf(dw3, dtr[l][3], db))));
                dtv = (dtv > 20.f) ? dtv : log1pf(__expf(dtv));
                float uv = XI[l][d];
                float dA = __expf(dtv * Aval);
                h = fmaf(dA, h, dtv * Bm[l][n] * uv);
                float part = h * Cm[l][n];
                part += __shfl_xor(part, 1, 4);
                part += __shfl_xor(part, 2, 4);
                if (n == 0) {
                    float yv = part + dpv * uv;
                    float zv = X[l][d];                  // z parked in X
                    Yb[l][d] = yv * (zv / (1.f + __expf(-zv)));
                }
            }
        }
        __syncthreads();

        // ---- out-projection: out[l][e] = dot(Yb[l], ow[e])
        {
            int eo = t & 63, lg = t >> 6;
            const float4* o4 = (const float4*)(P.ow + eo * 64);
#pragma unroll 4
            for (int ii = 0; ii < 16; ++ii) {
                int l = lg * 16 + ii;
                float acc0 = 0.f, acc1 = 0.f;
#pragma unroll
                for (int k4 = 0; k4 < 16; ++k4) {
                    float4 wv = o4[k4];
                    int k = k4 * 4;
                    acc0 = fmaf(Yb[l][k], wv.x, acc0);
                    acc1 = fmaf(Yb[l][k + 1], wv.y, acc1);
                    acc0 = fmaf(Yb[l][k + 2], wv.z, acc0);
                    acc1 = fmaf(Yb[l][k + 3], wv.w, acc1);
                }
                float acc = acc0 + acc1;
                if (blk == 0) X[l][eo] = acc;
                else out[b * 4096 + l * 64 + eo] = acc;
            }
        }
        __syncthreads();
    }
}

extern "C" void kernel_launch(void* const* d_in, const int* in_sizes, int n_in,
                              void* d_out, int out_size, void* d_ws, size_t ws_size,
                              hipStream_t stream) {
    const float* x   = (const float*)d_in[0];
    const float* c1w = (const float*)d_in[1];
    const float* c1b = (const float*)d_in[2];
    const float* c2w = (const float*)d_in[3];
    const float* c2b = (const float*)d_in[4];
    const float* c3w = (const float*)d_in[5];
    const float* c3b = (const float*)d_in[6];
    const float* lw  = (const float*)d_in[7];
    const float* lb  = (const float*)d_in[8];

    MambaP p1, p2;
    p1.lng = (const float*)d_in[9];  p1.lnb = (const float*)d_in[10];
    p1.inw = (const float*)d_in[11]; p1.cvw = (const float*)d_in[12];
    p1.cvb = (const float*)d_in[13]; p1.xpw = (const float*)d_in[14];
    p1.dtw = (const float*)d_in[15]; p1.dtb = (const float*)d_in[16];
    p1.al  = (const float*)d_in[17]; p1.dp  = (const float*)d_in[18];
    p1.ow  = (const float*)d_in[19];
    p2.lng = (const float*)d_in[20]; p2.lnb = (const float*)d_in[21];
    p2.inw = (const float*)d_in[22]; p2.cvw = (const float*)d_in[23];
    p2.cvb = (const float*)d_in[24]; p2.xpw = (const float*)d_in[25];
    p2.dtw = (const float*)d_in[26]; p2.dtb = (const float*)d_in[27];
    p2.al  = (const float*)d_in[28]; p2.dp  = (const float*)d_in[29];
    p2.ow  = (const float*)d_in[30];

    float* ws = (float*)d_ws;
    float* h1  = ws;                  // 16,777,216 floats [512,16,2048]
    float* h2  = ws + 16777216;       // 16,777,216 floats [512,32,1024]
    float* h3  = ws;                  // reuse h1 region: 1,048,576 floats [512,2048]
    float* lin = ws + 1048576;        // 2,097,152 floats [512,64,64]
    float* outp = (float*)d_out;

    conv1_pool<<<dim3(NB * 16 * 2048 / 256), dim3(256), 0, stream>>>(x, c1w, c1b, h1);
    conv2_pool<<<dim3(NB * 32 * 1024 / 256), dim3(256), 0, stream>>>(h1, c2w, c2b, h2);
    conv3_pool<<<dim3(NB * 64 * 32 / 256), dim3(256), 0, stream>>>(h2, c3w, c3b, h3);
    lin_gemm<<<dim3(4096 / 64, NB / 64), dim3(256), 0, stream>>>(h3, lw, lb, lin);
    mamba2_kernel<<<dim3(NB), dim3(256), 0, stream>>>(lin, p1, p2, outp);
}

// Round 2
// 757.207 us; speedup vs baseline: 2.7308x; 2.7308x over previous
//
#include <hip/hip_runtime.h>
#include <hip/hip_bf16.h>
#include <math.h>

#define NB 512

// ---------------- conv1: [B,1,4096] -> conv(k5,pad2)+relu+maxpool2 -> [B,16,2048]
// one block per batch; input row staged in LDS
__global__ __launch_bounds__(256) void conv1_pool(const float* __restrict__ x,
                                                  const float* __restrict__ w,
                                                  const float* __restrict__ bias,
                                                  float* __restrict__ out) {
    __shared__ float xs[4100];   // [pad2 | 4096 | pad2]
    int t = threadIdx.x, b = blockIdx.x;
    const float4* xb4 = (const float4*)(x + b * 4096);
    for (int i = t; i < 1024; i += 256) {
        float4 v = xb4[i];
        float* d = xs + 2 + i * 4;
        d[0] = v.x; d[1] = v.y; d[2] = v.z; d[3] = v.w;
    }
    if (t == 0) { xs[0] = xs[1] = 0.f; xs[4098] = xs[4099] = 0.f; }
    __syncthreads();
    int li = t & 63, cg = t >> 6;
    for (int cc = 0; cc < 4; ++cc) {
        int c = cc * 4 + cg;
        const float* wr = w + c * 5;
        float w0 = wr[0], w1 = wr[1], w2 = wr[2], w3 = wr[3], w4 = wr[4];
        float bv = bias[c];
        float* o = out + (b * 16 + c) * 2048;
        for (int chunk = 0; chunk < 32; ++chunk) {
            int lp = chunk * 64 + li;
            const float* s = xs + 2 * lp;   // conv at l0=2*lp reads xs[2+l0-2 ..] = xs[2*lp ..]
            float s0 = s[0], s1 = s[1], s2 = s[2], s3 = s[3], s4 = s[4], s5 = s[5];
            float v0 = fmaf(w0, s0, fmaf(w1, s1, fmaf(w2, s2, fmaf(w3, s3, fmaf(w4, s4, bv)))));
            float v1 = fmaf(w0, s1, fmaf(w1, s2, fmaf(w2, s3, fmaf(w3, s4, fmaf(w4, s5, bv)))));
            o[lp] = fmaxf(fmaxf(v0, v1), 0.f);
        }
    }
}

// ---------------- conv2: [B,16,2048] -> conv(k5,pad2)+relu+maxpool2 -> [B,32,1024]
// block = (tile of 128 pooled outputs, batch). LDS slab 16x260, padded weights.
__global__ __launch_bounds__(256) void conv2_pool(const float* __restrict__ h1,
                                                  const float* __restrict__ w,
                                                  const float* __restrict__ bias,
                                                  float* __restrict__ out) {
    __shared__ float in_s[16 * 260];   // in_s[c1*260+q] = input[c1][p0+q-2]
    __shared__ float w_s[80 * 33];     // w_s[(c1*5+k)*33 + c2]
    __shared__ float b_s[32];
    int t = threadIdx.x;
    int tile = blockIdx.x, b = blockIdx.y;
    int p0 = tile * 256;    // input position base
    int j0 = tile * 128;    // pooled output base
    const float* hb = h1 + b * 16 * 2048;
    for (int i = t; i < 16 * 260; i += 256) {
        int c1 = i / 260, q = i - c1 * 260;
        int g = p0 + q - 2;
        in_s[i] = (g >= 0 && g < 2048) ? hb[c1 * 2048 + g] : 0.f;
    }
    for (int i = t; i < 2560; i += 256) {
        int c2 = i / 80, rest = i - c2 * 80;   // rest = c1*5+k
        w_s[rest * 33 + c2] = w[c2 * 80 + rest];
    }
    if (t < 32) b_s[t] = bias[t];
    __syncthreads();

    int c2 = t & 31, seg = t >> 5;          // seg covers 16 pooled outputs
    float bv = b_s[c2];
    float acc0[16], acc1[16];
#pragma unroll
    for (int o = 0; o < 16; ++o) { acc0[o] = bv; acc1[o] = bv; }
    for (int c1 = 0; c1 < 16; ++c1) {
        const float* wr = w_s + c1 * 5 * 33 + c2;
        float w0 = wr[0], w1 = wr[33], w2 = wr[66], w3 = wr[99], w4 = wr[132];
        const float* row = in_s + c1 * 260 + seg * 32;
#pragma unroll
        for (int jc = 0; jc < 2; ++jc) {
            float s[20];
            const float4* r4 = (const float4*)(row + jc * 16);
#pragma unroll
            for (int m = 0; m < 5; ++m) {
                float4 v = r4[m];
                s[4 * m] = v.x; s[4 * m + 1] = v.y; s[4 * m + 2] = v.z; s[4 * m + 3] = v.w;
            }
#pragma unroll
            for (int jj = 0; jj < 8; ++jj) {
                int o = jc * 8 + jj;
                const float* sp = s + 2 * jj;
                acc0[o] = fmaf(w0, sp[0], fmaf(w1, sp[1], fmaf(w2, sp[2], fmaf(w3, sp[3], fmaf(w4, sp[4], acc0[o])))));
                acc1[o] = fmaf(w0, sp[1], fmaf(w1, sp[2], fmaf(w2, sp[3], fmaf(w3, sp[4], fmaf(w4, sp[5], acc1[o])))));
            }
        }
    }
    __syncthreads();
    // park results in LDS (reuse in_s; 32*130 = 4160 = 16*260) for coalesced stores
    float* outs = in_s;
#pragma unroll
    for (int o = 0; o < 16; ++o)
        outs[c2 * 130 + seg * 16 + o] = fmaxf(fmaxf(acc0[o], acc1[o]), 0.f);
    __syncthreads();
    float* ob = out + (b * 32) * 1024 + j0;
    for (int i = t; i < 32 * 128; i += 256) {
        int cc = i >> 7, pos = i & 127;
        ob[cc * 1024 + pos] = outs[cc * 130 + pos];
    }
}

// ---------------- conv3 + relu + adaptive avg pool(32): [B,32,1024] -> [B,2048]
// block = (quarter of 256 positions = 8 pool windows, batch)
__global__ __launch_bounds__(256) void conv3_pool(const float* __restrict__ h2,
                                                  const float* __restrict__ w,
                                                  const float* __restrict__ bias,
                                                  float* __restrict__ h3) {
    __shared__ float in_s[32 * 260];   // 33.3 KB : in_s[c1*260+q] = input[c1][p0+q-2]
    __shared__ float w_s[160 * 65];    // 41.6 KB : w_s[(c1*5+k)*65 + c3]
    __shared__ float b_s[64];
    int t = threadIdx.x;
    int qtr = blockIdx.x, b = blockIdx.y;
    int p0 = qtr * 256;
    const float* hb = h2 + b * 32 * 1024;
    for (int i = t; i < 32 * 260; i += 256) {
        int c1 = i / 260, q = i - c1 * 260;
        int g = p0 + q - 2;
        in_s[i] = (g >= 0 && g < 1024) ? hb[c1 * 1024 + g] : 0.f;
    }
    for (int i = t; i < 64 * 160; i += 256) {
        int c3 = i / 160, rest = i - c3 * 160;
        w_s[rest * 65 + c3] = w[c3 * 160 + rest];
    }
    if (t < 64) b_s[t] = bias[t];
    __syncthreads();

    int c3 = t & 63, wgrp = t >> 6;
    float bv = b_s[c3];
#pragma unroll 1
    for (int ww = 0; ww < 2; ++ww) {
        int w_id = wgrp * 2 + ww;      // pool window within quarter (0..7)
        int pl0 = w_id * 32;           // local position base
        float acc[32];
#pragma unroll
        for (int j = 0; j < 32; ++j) acc[j] = bv;
        for (int c1 = 0; c1 < 32; ++c1) {
            const float* wr = w_s + c1 * 5 * 65 + c3;
            float w0 = wr[0], w1 = wr[65], w2 = wr[130], w3 = wr[195], w4 = wr[260];
            float s[36];
            const float4* r4 = (const float4*)(in_s + c1 * 260 + pl0);
#pragma unroll
            for (int m = 0; m < 9; ++m) {
                float4 v = r4[m];
                s[4 * m] = v.x; s[4 * m + 1] = v.y; s[4 * m + 2] = v.z; s[4 * m + 3] = v.w;
            }
#pragma unroll
            for (int j = 0; j < 32; ++j)
                acc[j] = fmaf(w0, s[j], fmaf(w1, s[j + 1], fmaf(w2, s[j + 2],
                          fmaf(w3, s[j + 3], fmaf(w4, s[j + 4], acc[j])))));
        }
        float sum = 0.f;
#pragma unroll
        for (int j = 0; j < 32; ++j) sum += fmaxf(acc[j], 0.f);
        h3[b * 2048 + c3 * 32 + qtr * 8 + w_id] = sum * (1.f / 32.f);
    }
}

// ---------------- GEMM: C[512,4096] = h3[512,2048] @ lw[4096,2048]^T + lb
__global__ __launch_bounds__(256) void lin_gemm(const float* __restrict__ A,
                                                const float* __restrict__ Bw,
                                                const float* __restrict__ bias,
                                                float* __restrict__ C) {
    __shared__ float As[16][68];
    __shared__ float Bs[16][68];
    int t  = threadIdx.x;
    int tx = t & 15, ty = t >> 4;
    int row0 = blockIdx.y * 64;
    int col0 = blockIdx.x * 64;
    float acc[4][4] = {};
    for (int k0 = 0; k0 < 2048; k0 += 16) {
        for (int i = t; i < 64 * 16; i += 256) {
            int r = i >> 4, c = i & 15;
            As[c][r] = A[(row0 + r) * 2048 + k0 + c];
            Bs[c][r] = Bw[(col0 + r) * 2048 + k0 + c];
        }
        __syncthreads();
#pragma unroll
        for (int kk = 0; kk < 16; ++kk) {
            float a[4], bv[4];
#pragma unroll
            for (int i = 0; i < 4; ++i) a[i] = As[kk][ty * 4 + i];
#pragma unroll
            for (int j = 0; j < 4; ++j) bv[j] = Bs[kk][tx * 4 + j];
#pragma unroll
            for (int i = 0; i < 4; ++i)
#pragma unroll
                for (int j = 0; j < 4; ++j)
                    acc[i][j] = fmaf(a[i], bv[j], acc[i][j]);
        }
        __syncthreads();
    }
    int rbase = row0 + ty * 4, cbase = col0 + tx * 4;
#pragma unroll
    for (int i = 0; i < 4; ++i)
#pragma unroll
        for (int j = 0; j < 4; ++j)
            C[(rbase + i) * 4096 + cbase + j] = acc[i][j] + bias[cbase + j];
}

// ---------------- fused double {layernorm + mamba}: [B,64,64] -> [B,64,64]
struct MambaP {
    const float *lng, *lnb, *inw, *cvw, *cvb, *xpw, *dtw, *dtb, *al, *dp, *ow;
};

__global__ __launch_bounds__(256) void mamba2_kernel(const float* __restrict__ lin,
                                                     MambaP p1, MambaP p2,
                                                     float* __restrict__ out) {
    __shared__ float X[64][65];    // input -> xln -> z -> out1
    __shared__ float XI[64][65];   // xi -> u (in place)
    __shared__ float Yb[64][65];   // y before out-proj
    __shared__ float dtr[64][4], Bm[64][4], Cm[64][4];
    int b = blockIdx.x, t = threadIdx.x;

    for (int i = t; i < 4096; i += 256) X[i >> 6][i & 63] = lin[b * 4096 + i];
    __syncthreads();

    for (int blk = 0; blk < 2; ++blk) {
        MambaP P = blk ? p2 : p1;

        // ---- LayerNorm over d (in place), one thread per row l
        if (t < 64) {
            int l = t;
            float m = 0.f;
#pragma unroll
            for (int d = 0; d < 64; ++d) m += X[l][d];
            m *= (1.f / 64.f);
            float v = 0.f;
#pragma unroll
            for (int d = 0; d < 64; ++d) { float df = X[l][d] - m; v = fmaf(df, df, v); }
            v *= (1.f / 64.f);
            float rstd = rsqrtf(v + 1e-5f);
#pragma unroll
            for (int d = 0; d < 64; ++d)
                X[l][d] = (X[l][d] - m) * rstd * P.lng[d] + P.lnb[d];
        }
        __syncthreads();

        // ---- in-projection
        {
            int e = t & 127, half = t >> 7;
            const float4* w4 = (const float4*)(P.inw + e * 64);
            float zreg[32];
#pragma unroll 4
            for (int i = 0; i < 32; ++i) {
                int l = half * 32 + i;
                float acc0 = 0.f, acc1 = 0.f;
#pragma unroll
                for (int k4 = 0; k4 < 16; ++k4) {
                    float4 wv = w4[k4];
                    int k = k4 * 4;
                    acc0 = fmaf(X[l][k], wv.x, acc0);
                    acc1 = fmaf(X[l][k + 1], wv.y, acc1);
                    acc0 = fmaf(X[l][k + 2], wv.z, acc0);
                    acc1 = fmaf(X[l][k + 3], wv.w, acc1);
                }
                float acc = acc0 + acc1;
                if (e < 64) XI[l][e] = acc; else zreg[i] = acc;
            }
            __syncthreads();
            if (e >= 64) {
                int d = e - 64;
#pragma unroll 4
                for (int i = 0; i < 32; ++i) X[half * 32 + i][d] = zreg[i];
            }
        }
        __syncthreads();

        // ---- causal depthwise conv(k=2) + silu
        if (t < 64) {
            int d = t;
            float w0 = P.cvw[d * 2], w1 = P.cvw[d * 2 + 1], cb = P.cvb[d];
            float prev = 0.f;
            for (int l = 0; l < 64; ++l) {
                float cur = XI[l][d];
                float v = fmaf(w0, prev, fmaf(w1, cur, cb));
                XI[l][d] = v / (1.f + __expf(-v));
                prev = cur;
            }
        }
        __syncthreads();

        // ---- x_dbl = u @ xpw^T
        {
            int l = t & 63, jg = t >> 6;
#pragma unroll
            for (int jj = 0; jj < 3; ++jj) {
                int j = jg * 3 + jj;
                const float* xr = P.xpw + j * 64;
                float acc0 = 0.f, acc1 = 0.f;
#pragma unroll
                for (int k = 0; k < 64; k += 2) {
                    acc0 = fmaf(XI[l][k], xr[k], acc0);
                    acc1 = fmaf(XI[l][k + 1], xr[k + 1], acc1);
                }
                float acc = acc0 + acc1;
                if (j < 4) dtr[l][j] = acc;
                else if (j < 8) Bm[l][j - 4] = acc;
                else Cm[l][j - 8] = acc;
            }
        }
        __syncthreads();

        // ---- selective scan
        {
            int d = t >> 2, n = t & 3;
            float Aval = -__expf(P.al[d * 4 + n]);
            float dw0 = P.dtw[d * 4], dw1 = P.dtw[d * 4 + 1], dw2 = P.dtw[d * 4 + 2], dw3 = P.dtw[d * 4 + 3];
            float db = P.dtb[d], dpv = P.dp[d];
            float h = 0.f;
            for (int l = 0; l < 64; ++l) {
                float dtv = fmaf(dw0, dtr[l][0], fmaf(dw1, dtr[l][1],
                            fmaf(dw2, dtr[l][2], fmaf(dw3, dtr[l][3], db))));
                dtv = (dtv > 20.f) ? dtv : log1pf(__expf(dtv));
                float uv = XI[l][d];
                float dA = __expf(dtv * Aval);
                h = fmaf(dA, h, dtv * Bm[l][n] * uv);
                float part = h * Cm[l][n];
                part += __shfl_xor(part, 1, 4);
                part += __shfl_xor(part, 2, 4);
                if (n == 0) {
                    float yv = part + dpv * uv;
                    float zv = X[l][d];
                    Yb[l][d] = yv * (zv / (1.f + __expf(-zv)));
                }
            }
        }
        __syncthreads();

        // ---- out-projection
        {
            int eo = t & 63, lg = t >> 6;
            const float4* o4 = (const float4*)(P.ow + eo * 64);
#pragma unroll 4
            for (int ii = 0; ii < 16; ++ii) {
                int l = lg * 16 + ii;
                float acc0 = 0.f, acc1 = 0.f;
#pragma unroll
                for (int k4 = 0; k4 < 16; ++k4) {
                    float4 wv = o4[k4];
                    int k = k4 * 4;
                    acc0 = fmaf(Yb[l][k], wv.x, acc0);
                    acc1 = fmaf(Yb[l][k + 1], wv.y, acc1);
                    acc0 = fmaf(Yb[l][k + 2], wv.z, acc0);
                    acc1 = fmaf(Yb[l][k + 3], wv.w, acc1);
                }
                float acc = acc0 + acc1;
                if (blk == 0) X[l][eo] = acc;
                else out[b * 4096 + l * 64 + eo] = acc;
            }
        }
        __syncthreads();
    }
}

extern "C" void kernel_launch(void* const* d_in, const int* in_sizes, int n_in,
                              void* d_out, int out_size, void* d_ws, size_t ws_size,
                              hipStream_t stream) {
    const float* x   = (const float*)d_in[0];
    const float* c1w = (const float*)d_in[1];
    const float* c1b = (const float*)d_in[2];
    const float* c2w = (const float*)d_in[3];
    const float* c2b = (const float*)d_in[4];
    const float* c3w = (const float*)d_in[5];
    const float* c3b = (const float*)d_in[6];
    const float* lw  = (const float*)d_in[7];
    const float* lb  = (const float*)d_in[8];

    MambaP p1, p2;
    p1.lng = (const float*)d_in[9];  p1.lnb = (const float*)d_in[10];
    p1.inw = (const float*)d_in[11]; p1.cvw = (const float*)d_in[12];
    p1.cvb = (const float*)d_in[13]; p1.xpw = (const float*)d_in[14];
    p1.dtw = (const float*)d_in[15]; p1.dtb = (const float*)d_in[16];
    p1.al  = (const float*)d_in[17]; p1.dp  = (const float*)d_in[18];
    p1.ow  = (const float*)d_in[19];
    p2.lng = (const float*)d_in[20]; p2.lnb = (const float*)d_in[21];
    p2.inw = (const float*)d_in[22]; p2.cvw = (const float*)d_in[23];
    p2.cvb = (const float*)d_in[24]; p2.xpw = (const float*)d_in[25];
    p2.dtw = (const float*)d_in[26]; p2.dtb = (const float*)d_in[27];
    p2.al  = (const float*)d_in[28]; p2.dp  = (const float*)d_in[29];
    p2.ow  = (const float*)d_in[30];

    float* ws = (float*)d_ws;
    float* h1  = ws;                  // [512,16,2048]
    float* h2  = ws + 16777216;       // [512,32,1024]
    float* h3  = ws;                  // reuse h1 region: [512,2048]
    float* lin = ws + 1048576;        // [512,64,64]
    float* outp = (float*)d_out;

    conv1_pool<<<dim3(NB), dim3(256), 0, stream>>>(x, c1w, c1b, h1);
    conv2_pool<<<dim3(8, NB), dim3(256), 0, stream>>>(h1, c2w, c2b, h2);
    conv3_pool<<<dim3(4, NB), dim3(256), 0, stream>>>(h2, c3w, c3b, h3);
    lin_gemm<<<dim3(4096 / 64, NB / 64), dim3(256), 0, stream>>>(h3, lw, lb, lin);
    mamba2_kernel<<<dim3(NB), dim3(256), 0, stream>>>(lin, p1, p2, outp);
}

// Round 3
// 570.441 us; speedup vs baseline: 3.6249x; 1.3274x over previous
//
#include <hip/hip_runtime.h>
#include <hip/hip_bf16.h>
#include <math.h>

#define NB 512

typedef __attribute__((ext_vector_type(8))) short short8;
typedef __attribute__((ext_vector_type(4))) float f32x4;
union U4 { uint4 u; short8 s8; };

// ---------------- conv1: [B,1,4096] -> conv(k5,pad2)+relu+maxpool2 -> [B,16,2048]
__global__ __launch_bounds__(256) void conv1_pool(const float* __restrict__ x,
                                                  const float* __restrict__ w,
                                                  const float* __restrict__ bias,
                                                  float* __restrict__ out) {
    __shared__ float xs[4100];   // [pad2 | 4096 | pad2]
    int t = threadIdx.x, b = blockIdx.x;
    const float4* xb4 = (const float4*)(x + b * 4096);
    for (int i = t; i < 1024; i += 256) {
        float4 v = xb4[i];
        float* d = xs + 2 + i * 4;
        d[0] = v.x; d[1] = v.y; d[2] = v.z; d[3] = v.w;
    }
    if (t == 0) { xs[0] = xs[1] = 0.f; xs[4098] = xs[4099] = 0.f; }
    __syncthreads();
    int li = t & 63, cg = t >> 6;
    for (int cc = 0; cc < 4; ++cc) {
        int c = cc * 4 + cg;
        const float* wr = w + c * 5;
        float w0 = wr[0], w1 = wr[1], w2 = wr[2], w3 = wr[3], w4 = wr[4];
        float bv = bias[c];
        float* o = out + (b * 16 + c) * 2048;
        for (int chunk = 0; chunk < 32; ++chunk) {
            int lp = chunk * 64 + li;
            const float* s = xs + 2 * lp;
            float s0 = s[0], s1 = s[1], s2 = s[2], s3 = s[3], s4 = s[4], s5 = s[5];
            float v0 = fmaf(w0, s0, fmaf(w1, s1, fmaf(w2, s2, fmaf(w3, s3, fmaf(w4, s4, bv)))));
            float v1 = fmaf(w0, s1, fmaf(w1, s2, fmaf(w2, s3, fmaf(w3, s4, fmaf(w4, s5, bv)))));
            o[lp] = fmaxf(fmaxf(v0, v1), 0.f);
        }
    }
}

// ---------------- conv2: [B,16,2048] -> conv(k5,pad2)+relu+maxpool2 -> [B,32,1024]
__global__ __launch_bounds__(256) void conv2_pool(const float* __restrict__ h1,
                                                  const float* __restrict__ w,
                                                  const float* __restrict__ bias,
                                                  float* __restrict__ out) {
    __shared__ float in_s[16 * 260];
    __shared__ float w_s[80 * 33];
    __shared__ float b_s[32];
    int t = threadIdx.x;
    int tile = blockIdx.x, b = blockIdx.y;
    int p0 = tile * 256;
    int j0 = tile * 128;
    const float* hb = h1 + b * 16 * 2048;
    for (int i = t; i < 16 * 260; i += 256) {
        int c1 = i / 260, q = i - c1 * 260;
        int g = p0 + q - 2;
        in_s[i] = (g >= 0 && g < 2048) ? hb[c1 * 2048 + g] : 0.f;
    }
    for (int i = t; i < 2560; i += 256) {
        int c2 = i / 80, rest = i - c2 * 80;
        w_s[rest * 33 + c2] = w[c2 * 80 + rest];
    }
    if (t < 32) b_s[t] = bias[t];
    __syncthreads();

    int c2 = t & 31, seg = t >> 5;
    float bv = b_s[c2];
    float acc0[16], acc1[16];
#pragma unroll
    for (int o = 0; o < 16; ++o) { acc0[o] = bv; acc1[o] = bv; }
    for (int c1 = 0; c1 < 16; ++c1) {
        const float* wr = w_s + c1 * 5 * 33 + c2;
        float w0 = wr[0], w1 = wr[33], w2 = wr[66], w3 = wr[99], w4 = wr[132];
        const float* row = in_s + c1 * 260 + seg * 32;
#pragma unroll
        for (int jc = 0; jc < 2; ++jc) {
            float s[20];
            const float4* r4 = (const float4*)(row + jc * 16);
#pragma unroll
            for (int m = 0; m < 5; ++m) {
                float4 v = r4[m];
                s[4 * m] = v.x; s[4 * m + 1] = v.y; s[4 * m + 2] = v.z; s[4 * m + 3] = v.w;
            }
#pragma unroll
            for (int jj = 0; jj < 8; ++jj) {
                int o = jc * 8 + jj;
                const float* sp = s + 2 * jj;
                acc0[o] = fmaf(w0, sp[0], fmaf(w1, sp[1], fmaf(w2, sp[2], fmaf(w3, sp[3], fmaf(w4, sp[4], acc0[o])))));
                acc1[o] = fmaf(w0, sp[1], fmaf(w1, sp[2], fmaf(w2, sp[3], fmaf(w3, sp[4], fmaf(w4, sp[5], acc1[o])))));
            }
        }
    }
    __syncthreads();
    float* outs = in_s;
#pragma unroll
    for (int o = 0; o < 16; ++o)
        outs[c2 * 130 + seg * 16 + o] = fmaxf(fmaxf(acc0[o], acc1[o]), 0.f);
    __syncthreads();
    float* ob = out + (b * 32) * 1024 + j0;
    for (int i = t; i < 32 * 128; i += 256) {
        int cc = i >> 7, pos = i & 127;
        ob[cc * 1024 + pos] = outs[cc * 130 + pos];
    }
}

// ---------------- conv3 + relu + adaptive avg pool(32): [B,32,1024] -> [B,2048] (bf16 out)
__global__ __launch_bounds__(256) void conv3_pool(const float* __restrict__ h2,
                                                  const float* __restrict__ w,
                                                  const float* __restrict__ bias,
                                                  __hip_bfloat16* __restrict__ h3b) {
    __shared__ float in_s[32 * 260];
    __shared__ float w_s[160 * 65];
    __shared__ float b_s[64];
    int t = threadIdx.x;
    int qtr = blockIdx.x, b = blockIdx.y;
    int p0 = qtr * 256;
    const float* hb = h2 + b * 32 * 1024;
    for (int i = t; i < 32 * 260; i += 256) {
        int c1 = i / 260, q = i - c1 * 260;
        int g = p0 + q - 2;
        in_s[i] = (g >= 0 && g < 1024) ? hb[c1 * 1024 + g] : 0.f;
    }
    for (int i = t; i < 64 * 160; i += 256) {
        int c3 = i / 160, rest = i - c3 * 160;
        w_s[rest * 65 + c3] = w[c3 * 160 + rest];
    }
    if (t < 64) b_s[t] = bias[t];
    __syncthreads();

    int c3 = t & 63, wgrp = t >> 6;
    float bv = b_s[c3];
#pragma unroll 1
    for (int ww = 0; ww < 2; ++ww) {
        int w_id = wgrp * 2 + ww;
        int pl0 = w_id * 32;
        float acc[32];
#pragma unroll
        for (int j = 0; j < 32; ++j) acc[j] = bv;
        for (int c1 = 0; c1 < 32; ++c1) {
            const float* wr = w_s + c1 * 5 * 65 + c3;
            float w0 = wr[0], w1 = wr[65], w2 = wr[130], w3 = wr[195], w4 = wr[260];
            float s[36];
            const float4* r4 = (const float4*)(in_s + c1 * 260 + pl0);
#pragma unroll
            for (int m = 0; m < 9; ++m) {
                float4 v = r4[m];
                s[4 * m] = v.x; s[4 * m + 1] = v.y; s[4 * m + 2] = v.z; s[4 * m + 3] = v.w;
            }
#pragma unroll
            for (int j = 0; j < 32; ++j)
                acc[j] = fmaf(w0, s[j], fmaf(w1, s[j + 1], fmaf(w2, s[j + 2],
                          fmaf(w3, s[j + 3], fmaf(w4, s[j + 4], acc[j])))));
        }
        float sum = 0.f;
#pragma unroll
        for (int j = 0; j < 32; ++j) sum += fmaxf(acc[j], 0.f);
        h3b[b * 2048 + c3 * 32 + qtr * 8 + w_id] = __float2bfloat16(sum * (1.f / 32.f));
    }
}

// ---------------- lw fp32 -> bf16 (run once per launch)
__global__ __launch_bounds__(256) void lw_to_bf16(const float4* __restrict__ in,
                                                  ushort4* __restrict__ out) {
    int i = blockIdx.x * 256 + threadIdx.x;   // 2,097,152 float4s
    float4 v = in[i];
    union { ushort4 u; __hip_bfloat16 h[4]; } o;
    o.h[0] = __float2bfloat16(v.x);
    o.h[1] = __float2bfloat16(v.y);
    o.h[2] = __float2bfloat16(v.z);
    o.h[3] = __float2bfloat16(v.w);
    out[i] = o.u;
}

// ---------------- MFMA GEMM: C[512,4096] = A[512,2048]bf16 @ B[4096,2048]bf16^T + lb
// tile 64(M) x 128(N), BK=64, grid (32,8) = 256 blocks
__global__ __launch_bounds__(256) void lin_gemm_mfma(const __hip_bfloat16* __restrict__ A,
                                                     const __hip_bfloat16* __restrict__ B,
                                                     const float* __restrict__ bias,
                                                     float* __restrict__ C) {
    __shared__ uint4 A_s[64 * 8];    // [r][u^(r&7)] : 8 bf16 units, 8 KB
    __shared__ uint4 B_s[128 * 8];   // 16 KB
    int t = threadIdx.x;
    int col0 = blockIdx.x * 128;
    int row0 = blockIdx.y * 64;
    int w = t >> 6, lane = t & 63;
    int m = lane & 15, quad = lane >> 4;

    f32x4 acc[8];
#pragma unroll
    for (int nt = 0; nt < 8; ++nt) acc[nt] = (f32x4){0.f, 0.f, 0.f, 0.f};

    for (int ki = 0; ki < 32; ++ki) {
        int k0 = ki * 64;
#pragma unroll
        for (int p = 0; p < 2; ++p) {
            int id = p * 256 + t;
            int r = id >> 3, u = id & 7;
            A_s[r * 8 + (u ^ (r & 7))] = *(const uint4*)(A + (row0 + r) * 2048 + k0 + u * 8);
        }
#pragma unroll
        for (int p = 0; p < 4; ++p) {
            int id = p * 256 + t;
            int r = id >> 3, u = id & 7;
            B_s[r * 8 + (u ^ (r & 7))] = *(const uint4*)(B + (col0 + r) * 2048 + k0 + u * 8);
        }
        __syncthreads();
#pragma unroll
        for (int c = 0; c < 2; ++c) {
            int ra = w * 16 + m;
            int ua = c * 4 + quad;
            U4 av; av.u = A_s[ra * 8 + (ua ^ (ra & 7))];
#pragma unroll
            for (int nt = 0; nt < 8; ++nt) {
                int rb = nt * 16 + m;
                U4 bv; bv.u = B_s[rb * 8 + (ua ^ (rb & 7))];
                acc[nt] = __builtin_amdgcn_mfma_f32_16x16x32_bf16(av.s8, bv.s8, acc[nt], 0, 0, 0);
            }
        }
        __syncthreads();
    }
#pragma unroll
    for (int nt = 0; nt < 8; ++nt) {
        int col = col0 + nt * 16 + m;
        float bv = bias[col];
#pragma unroll
        for (int reg = 0; reg < 4; ++reg) {
            int row = row0 + w * 16 + quad * 4 + reg;
            C[row * 4096 + col] = acc[nt][reg] + bv;
        }
    }
}

// ---------------- fused double {layernorm + mamba}: [B,64,64] -> [B,64,64]
struct MambaP {
    const float *lng, *lnb, *inw, *cvw, *cvb, *xpw, *dtw, *dtb, *al, *dp, *ow;
};

__global__ __launch_bounds__(256) void mamba2_kernel(const float* __restrict__ lin,
                                                     MambaP p1, MambaP p2,
                                                     float* __restrict__ out) {
    __shared__ float X[64][65];
    __shared__ float XI[64][65];
    __shared__ float Yb[64][65];
    __shared__ float dtr[64][4], Bm[64][4], Cm[64][4];
    int b = blockIdx.x, t = threadIdx.x;

    for (int i = t; i < 4096; i += 256) X[i >> 6][i & 63] = lin[b * 4096 + i];
    __syncthreads();

    for (int blk = 0; blk < 2; ++blk) {
        MambaP P = blk ? p2 : p1;

        if (t < 64) {
            int l = t;
            float m = 0.f;
#pragma unroll
            for (int d = 0; d < 64; ++d) m += X[l][d];
            m *= (1.f / 64.f);
            float v = 0.f;
#pragma unroll
            for (int d = 0; d < 64; ++d) { float df = X[l][d] - m; v = fmaf(df, df, v); }
            v *= (1.f / 64.f);
            float rstd = rsqrtf(v + 1e-5f);
#pragma unroll
            for (int d = 0; d < 64; ++d)
                X[l][d] = (X[l][d] - m) * rstd * P.lng[d] + P.lnb[d];
        }
        __syncthreads();

        {
            int e = t & 127, half = t >> 7;
            const float4* w4 = (const float4*)(P.inw + e * 64);
            float zreg[32];
#pragma unroll 4
            for (int i = 0; i < 32; ++i) {
                int l = half * 32 + i;
                float acc0 = 0.f, acc1 = 0.f;
#pragma unroll
                for (int k4 = 0; k4 < 16; ++k4) {
                    float4 wv = w4[k4];
                    int k = k4 * 4;
                    acc0 = fmaf(X[l][k], wv.x, acc0);
                    acc1 = fmaf(X[l][k + 1], wv.y, acc1);
                    acc0 = fmaf(X[l][k + 2], wv.z, acc0);
                    acc1 = fmaf(X[l][k + 3], wv.w, acc1);
                }
                float acc = acc0 + acc1;
                if (e < 64) XI[l][e] = acc; else zreg[i] = acc;
            }
            __syncthreads();
            if (e >= 64) {
                int d = e - 64;
#pragma unroll 4
                for (int i = 0; i < 32; ++i) X[half * 32 + i][d] = zreg[i];
            }
        }
        __syncthreads();

        if (t < 64) {
            int d = t;
            float w0 = P.cvw[d * 2], w1 = P.cvw[d * 2 + 1], cb = P.cvb[d];
            float prev = 0.f;
            for (int l = 0; l < 64; ++l) {
                float cur = XI[l][d];
                float v = fmaf(w0, prev, fmaf(w1, cur, cb));
                XI[l][d] = v / (1.f + __expf(-v));
                prev = cur;
            }
        }
        __syncthreads();

        {
            int l = t & 63, jg = t >> 6;
#pragma unroll
            for (int jj = 0; jj < 3; ++jj) {
                int j = jg * 3 + jj;
                const float* xr = P.xpw + j * 64;
                float acc0 = 0.f, acc1 = 0.f;
#pragma unroll
                for (int k = 0; k < 64; k += 2) {
                    acc0 = fmaf(XI[l][k], xr[k], acc0);
                    acc1 = fmaf(XI[l][k + 1], xr[k + 1], acc1);
                }
                float acc = acc0 + acc1;
                if (j < 4) dtr[l][j] = acc;
                else if (j < 8) Bm[l][j - 4] = acc;
                else Cm[l][j - 8] = acc;
            }
        }
        __syncthreads();

        {
            int d = t >> 2, n = t & 3;
            float Aval = -__expf(P.al[d * 4 + n]);
            float dw0 = P.dtw[d * 4], dw1 = P.dtw[d * 4 + 1], dw2 = P.dtw[d * 4 + 2], dw3 = P.dtw[d * 4 + 3];
            float db = P.dtb[d], dpv = P.dp[d];
            float h = 0.f;
            for (int l = 0; l < 64; ++l) {
                float dtv = fmaf(dw0, dtr[l][0], fmaf(dw1, dtr[l][1],
                            fmaf(dw2, dtr[l][2], fmaf(dw3, dtr[l][3], db))));
                dtv = (dtv > 20.f) ? dtv : log1pf(__expf(dtv));
                float uv = XI[l][d];
                float dA = __expf(dtv * Aval);
                h = fmaf(dA, h, dtv * Bm[l][n] * uv);
                float part = h * Cm[l][n];
                part += __shfl_xor(part, 1, 4);
                part += __shfl_xor(part, 2, 4);
                if (n == 0) {
                    float yv = part + dpv * uv;
                    float zv = X[l][d];
                    Yb[l][d] = yv * (zv / (1.f + __expf(-zv)));
                }
            }
        }
        __syncthreads();

        {
            int eo = t & 63, lg = t >> 6;
            const float4* o4 = (const float4*)(P.ow + eo * 64);
#pragma unroll 4
            for (int ii = 0; ii < 16; ++ii) {
                int l = lg * 16 + ii;
                float acc0 = 0.f, acc1 = 0.f;
#pragma unroll
                for (int k4 = 0; k4 < 16; ++k4) {
                    float4 wv = o4[k4];
                    int k = k4 * 4;
                    acc0 = fmaf(Yb[l][k], wv.x, acc0);
                    acc1 = fmaf(Yb[l][k + 1], wv.y, acc1);
                    acc0 = fmaf(Yb[l][k + 2], wv.z, acc0);
                    acc1 = fmaf(Yb[l][k + 3], wv.w, acc1);
                }
                float acc = acc0 + acc1;
                if (blk == 0) X[l][eo] = acc;
                else out[b * 4096 + l * 64 + eo] = acc;
            }
        }
        __syncthreads();
    }
}

extern "C" void kernel_launch(void* const* d_in, const int* in_sizes, int n_in,
                              void* d_out, int out_size, void* d_ws, size_t ws_size,
                              hipStream_t stream) {
    const float* x   = (const float*)d_in[0];
    const float* c1w = (const float*)d_in[1];
    const float* c1b = (const float*)d_in[2];
    const float* c2w = (const float*)d_in[3];
    const float* c2b = (const float*)d_in[4];
    const float* c3w = (const float*)d_in[5];
    const float* c3b = (const float*)d_in[6];
    const float* lw  = (const float*)d_in[7];
    const float* lb  = (const float*)d_in[8];

    MambaP p1, p2;
    p1.lng = (const float*)d_in[9];  p1.lnb = (const float*)d_in[10];
    p1.inw = (const float*)d_in[11]; p1.cvw = (const float*)d_in[12];
    p1.cvb = (const float*)d_in[13]; p1.xpw = (const float*)d_in[14];
    p1.dtw = (const float*)d_in[15]; p1.dtb = (const float*)d_in[16];
    p1.al  = (const float*)d_in[17]; p1.dp  = (const float*)d_in[18];
    p1.ow  = (const float*)d_in[19];
    p2.lng = (const float*)d_in[20]; p2.lnb = (const float*)d_in[21];
    p2.inw = (const float*)d_in[22]; p2.cvw = (const float*)d_in[23];
    p2.cvb = (const float*)d_in[24]; p2.xpw = (const float*)d_in[25];
    p2.dtw = (const float*)d_in[26]; p2.dtb = (const float*)d_in[27];
    p2.al  = (const float*)d_in[28]; p2.dp  = (const float*)d_in[29];
    p2.ow  = (const float*)d_in[30];

    char* base = (char*)d_ws;
    float* h1 = (float*)base;                                   // [0, 64 MiB)
    float* h2 = (float*)(base + (size_t)64 * 1024 * 1024);      // [64, 128 MiB)
    // after conv2, h1 region is dead -> reuse:
    __hip_bfloat16* lwb = (__hip_bfloat16*)base;                        // [0, 16 MiB)
    __hip_bfloat16* h3b = (__hip_bfloat16*)(base + (size_t)16 * 1024 * 1024);  // [16, 18 MiB)
    float* lin = (float*)(base + (size_t)18 * 1024 * 1024);             // [18, 26 MiB)
    float* outp = (float*)d_out;

    conv1_pool<<<dim3(NB), dim3(256), 0, stream>>>(x, c1w, c1b, h1);
    conv2_pool<<<dim3(8, NB), dim3(256), 0, stream>>>(h1, c2w, c2b, h2);
    lw_to_bf16<<<dim3(8192), dim3(256), 0, stream>>>((const float4*)lw, (ushort4*)lwb);
    conv3_pool<<<dim3(4, NB), dim3(256), 0, stream>>>(h2, c3w, c3b, h3b);
    lin_gemm_mfma<<<dim3(32, 8), dim3(256), 0, stream>>>(h3b, lwb, lb, lin);
    mamba2_kernel<<<dim3(NB), dim3(256), 0, stream>>>(lin, p1, p2, outp);
}

// Round 4
// 509.178 us; speedup vs baseline: 4.0611x; 1.1203x over previous
//
#include <hip/hip_runtime.h>
#include <hip/hip_bf16.h>
#include <math.h>

#define NB 512

typedef __attribute__((ext_vector_type(8))) short short8;
typedef __attribute__((ext_vector_type(4))) float f32x4;
union U4 { uint4 u; short8 s8; };

// ---------------- conv1: [B,1,4096] -> conv(k5,pad2)+relu+maxpool2 -> [B,16,2048]
__global__ __launch_bounds__(256) void conv1_pool(const float* __restrict__ x,
                                                  const float* __restrict__ w,
                                                  const float* __restrict__ bias,
                                                  float* __restrict__ out) {
    __shared__ float xs[4100];   // [pad2 | 4096 | pad2]
    int t = threadIdx.x, b = blockIdx.x;
    const float4* xb4 = (const float4*)(x + b * 4096);
    for (int i = t; i < 1024; i += 256) {
        float4 v = xb4[i];
        float* d = xs + 2 + i * 4;
        d[0] = v.x; d[1] = v.y; d[2] = v.z; d[3] = v.w;
    }
    if (t == 0) { xs[0] = xs[1] = 0.f; xs[4098] = xs[4099] = 0.f; }
    __syncthreads();
    int li = t & 63, cg = t >> 6;
    for (int cc = 0; cc < 4; ++cc) {
        int c = cc * 4 + cg;
        const float* wr = w + c * 5;
        float w0 = wr[0], w1 = wr[1], w2 = wr[2], w3 = wr[3], w4 = wr[4];
        float bv = bias[c];
        float* o = out + (b * 16 + c) * 2048;
        for (int chunk = 0; chunk < 32; ++chunk) {
            int lp = chunk * 64 + li;
            const float* s = xs + 2 * lp;
            float s0 = s[0], s1 = s[1], s2 = s[2], s3 = s[3], s4 = s[4], s5 = s[5];
            float v0 = fmaf(w0, s0, fmaf(w1, s1, fmaf(w2, s2, fmaf(w3, s3, fmaf(w4, s4, bv)))));
            float v1 = fmaf(w0, s1, fmaf(w1, s2, fmaf(w2, s3, fmaf(w3, s4, fmaf(w4, s5, bv)))));
            o[lp] = fmaxf(fmaxf(v0, v1), 0.f);
        }
    }
}

// ---------------- conv2: [B,16,2048] -> conv(k5,pad2)+relu+maxpool2 -> [B,32,1024]
__global__ __launch_bounds__(256) void conv2_pool(const float* __restrict__ h1,
                                                  const float* __restrict__ w,
                                                  const float* __restrict__ bias,
                                                  float* __restrict__ out) {
    __shared__ float in_s[16 * 260];
    __shared__ float w_s[80 * 33];
    __shared__ float b_s[32];
    int t = threadIdx.x;
    int tile = blockIdx.x, b = blockIdx.y;
    int p0 = tile * 256;
    int j0 = tile * 128;
    const float* hb = h1 + b * 16 * 2048;
    for (int i = t; i < 16 * 260; i += 256) {
        int c1 = i / 260, q = i - c1 * 260;
        int g = p0 + q - 2;
        in_s[i] = (g >= 0 && g < 2048) ? hb[c1 * 2048 + g] : 0.f;
    }
    for (int i = t; i < 2560; i += 256) {
        int c2 = i / 80, rest = i - c2 * 80;
        w_s[rest * 33 + c2] = w[c2 * 80 + rest];
    }
    if (t < 32) b_s[t] = bias[t];
    __syncthreads();

    int c2 = t & 31, seg = t >> 5;
    float bv = b_s[c2];
    float acc0[16], acc1[16];
#pragma unroll
    for (int o = 0; o < 16; ++o) { acc0[o] = bv; acc1[o] = bv; }
    for (int c1 = 0; c1 < 16; ++c1) {
        const float* wr = w_s + c1 * 5 * 33 + c2;
        float w0 = wr[0], w1 = wr[33], w2 = wr[66], w3 = wr[99], w4 = wr[132];
        const float* row = in_s + c1 * 260 + seg * 32;
#pragma unroll
        for (int jc = 0; jc < 2; ++jc) {
            float s[20];
            const float4* r4 = (const float4*)(row + jc * 16);
#pragma unroll
            for (int m = 0; m < 5; ++m) {
                float4 v = r4[m];
                s[4 * m] = v.x; s[4 * m + 1] = v.y; s[4 * m + 2] = v.z; s[4 * m + 3] = v.w;
            }
#pragma unroll
            for (int jj = 0; jj < 8; ++jj) {
                int o = jc * 8 + jj;
                const float* sp = s + 2 * jj;
                acc0[o] = fmaf(w0, sp[0], fmaf(w1, sp[1], fmaf(w2, sp[2], fmaf(w3, sp[3], fmaf(w4, sp[4], acc0[o])))));
                acc1[o] = fmaf(w0, sp[1], fmaf(w1, sp[2], fmaf(w2, sp[3], fmaf(w3, sp[4], fmaf(w4, sp[5], acc1[o])))));
            }
        }
    }
    __syncthreads();
    float* outs = in_s;
#pragma unroll
    for (int o = 0; o < 16; ++o)
        outs[c2 * 130 + seg * 16 + o] = fmaxf(fmaxf(acc0[o], acc1[o]), 0.f);
    __syncthreads();
    float* ob = out + (b * 32) * 1024 + j0;
    for (int i = t; i < 32 * 128; i += 256) {
        int cc = i >> 7, pos = i & 127;
        ob[cc * 1024 + pos] = outs[cc * 130 + pos];
    }
}

// ---------------- conv3 + relu + adaptive avg pool(32): [B,32,1024] -> [B,2048] (bf16 out)
__global__ __launch_bounds__(256) void conv3_pool(const float* __restrict__ h2,
                                                  const float* __restrict__ w,
                                                  const float* __restrict__ bias,
                                                  __hip_bfloat16* __restrict__ h3b) {
    __shared__ float in_s[32 * 260];
    __shared__ float w_s[160 * 65];
    __shared__ float b_s[64];
    int t = threadIdx.x;
    int qtr = blockIdx.x, b = blockIdx.y;
    int p0 = qtr * 256;
    const float* hb = h2 + b * 32 * 1024;
    for (int i = t; i < 32 * 260; i += 256) {
        int c1 = i / 260, q = i - c1 * 260;
        int g = p0 + q - 2;
        in_s[i] = (g >= 0 && g < 1024) ? hb[c1 * 1024 + g] : 0.f;
    }
    for (int i = t; i < 64 * 160; i += 256) {
        int c3 = i / 160, rest = i - c3 * 160;
        w_s[rest * 65 + c3] = w[c3 * 160 + rest];
    }
    if (t < 64) b_s[t] = bias[t];
    __syncthreads();

    int c3 = t & 63, wgrp = t >> 6;
    float bv = b_s[c3];
#pragma unroll 1
    for (int ww = 0; ww < 2; ++ww) {
        int w_id = wgrp * 2 + ww;
        int pl0 = w_id * 32;
        float acc[32];
#pragma unroll
        for (int j = 0; j < 32; ++j) acc[j] = bv;
        for (int c1 = 0; c1 < 32; ++c1) {
            const float* wr = w_s + c1 * 5 * 65 + c3;
            float w0 = wr[0], w1 = wr[65], w2 = wr[130], w3 = wr[195], w4 = wr[260];
            float s[36];
            const float4* r4 = (const float4*)(in_s + c1 * 260 + pl0);
#pragma unroll
            for (int m = 0; m < 9; ++m) {
                float4 v = r4[m];
                s[4 * m] = v.x; s[4 * m + 1] = v.y; s[4 * m + 2] = v.z; s[4 * m + 3] = v.w;
            }
#pragma unroll
            for (int j = 0; j < 32; ++j)
                acc[j] = fmaf(w0, s[j], fmaf(w1, s[j + 1], fmaf(w2, s[j + 2],
                          fmaf(w3, s[j + 3], fmaf(w4, s[j + 4], acc[j])))));
        }
        float sum = 0.f;
#pragma unroll
        for (int j = 0; j < 32; ++j) sum += fmaxf(acc[j], 0.f);
        h3b[b * 2048 + c3 * 32 + qtr * 8 + w_id] = __float2bfloat16(sum * (1.f / 32.f));
    }
}

// ---------------- lw fp32 -> bf16 (run once per launch)
__global__ __launch_bounds__(256) void lw_to_bf16(const float4* __restrict__ in,
                                                  ushort4* __restrict__ out) {
    int i = blockIdx.x * 256 + threadIdx.x;   // 2,097,152 float4s
    float4 v = in[i];
    union { ushort4 u; __hip_bfloat16 h[4]; } o;
    o.h[0] = __float2bfloat16(v.x);
    o.h[1] = __float2bfloat16(v.y);
    o.h[2] = __float2bfloat16(v.z);
    o.h[3] = __float2bfloat16(v.w);
    out[i] = o.u;
}

// ---------------- MFMA GEMM: C[512,4096] = A[512,2048]bf16 @ B[4096,2048]bf16^T + lb
__global__ __launch_bounds__(256) void lin_gemm_mfma(const __hip_bfloat16* __restrict__ A,
                                                     const __hip_bfloat16* __restrict__ B,
                                                     const float* __restrict__ bias,
                                                     float* __restrict__ C) {
    __shared__ uint4 A_s[64 * 8];
    __shared__ uint4 B_s[128 * 8];
    int t = threadIdx.x;
    int col0 = blockIdx.x * 128;
    int row0 = blockIdx.y * 64;
    int w = t >> 6, lane = t & 63;
    int m = lane & 15, quad = lane >> 4;

    f32x4 acc[8];
#pragma unroll
    for (int nt = 0; nt < 8; ++nt) acc[nt] = (f32x4){0.f, 0.f, 0.f, 0.f};

    for (int ki = 0; ki < 32; ++ki) {
        int k0 = ki * 64;
#pragma unroll
        for (int p = 0; p < 2; ++p) {
            int id = p * 256 + t;
            int r = id >> 3, u = id & 7;
            A_s[r * 8 + (u ^ (r & 7))] = *(const uint4*)(A + (row0 + r) * 2048 + k0 + u * 8);
        }
#pragma unroll
        for (int p = 0; p < 4; ++p) {
            int id = p * 256 + t;
            int r = id >> 3, u = id & 7;
            B_s[r * 8 + (u ^ (r & 7))] = *(const uint4*)(B + (col0 + r) * 2048 + k0 + u * 8);
        }
        __syncthreads();
#pragma unroll
        for (int c = 0; c < 2; ++c) {
            int ra = w * 16 + m;
            int ua = c * 4 + quad;
            U4 av; av.u = A_s[ra * 8 + (ua ^ (ra & 7))];
#pragma unroll
            for (int nt = 0; nt < 8; ++nt) {
                int rb = nt * 16 + m;
                U4 bv; bv.u = B_s[rb * 8 + (ua ^ (rb & 7))];
                acc[nt] = __builtin_amdgcn_mfma_f32_16x16x32_bf16(av.s8, bv.s8, acc[nt], 0, 0, 0);
            }
        }
        __syncthreads();
    }
#pragma unroll
    for (int nt = 0; nt < 8; ++nt) {
        int col = col0 + nt * 16 + m;
        float bv = bias[col];
#pragma unroll
        for (int reg = 0; reg < 4; ++reg) {
            int row = row0 + w * 16 + quad * 4 + reg;
            C[row * 4096 + col] = acc[nt][reg] + bv;
        }
    }
}

// ---------------- fused double {layernorm + mamba}: [B,64,64] -> [B,64,64]
struct MambaP {
    const float *lng, *lnb, *inw, *cvw, *cvb, *xpw, *dtw, *dtb, *al, *dp, *ow;
};

__global__ __launch_bounds__(256, 2) void mamba2_kernel(const float* __restrict__ lin,
                                                        MambaP p1, MambaP p2,
                                                        float* __restrict__ out) {
    __shared__ float X[64][68];    // input -> xln -> out1 (stride 68: 16B-aligned rows)
    __shared__ float XI[64][68];   // xi -> u (in place)
    __shared__ float Yb[64][68];   // z (from in-proj), then gated y (scan writes in place)
    __shared__ float DT[64][68];   // softplus(dt) TRANSPOSED: DT[d][l]
    __shared__ float dtr[64][5];   // stride 5: conflict-free column access
    __shared__ float Bm[64][4], Cm[64][4];
    int b = blockIdx.x, t = threadIdx.x;

    {
        const float4* lin4 = (const float4*)(lin + b * 4096);
        for (int i = t; i < 1024; i += 256) {
            float4 v = lin4[i];
            *(float4*)(&X[i >> 4][(i & 15) * 4]) = v;
        }
    }
    __syncthreads();

    for (int blk = 0; blk < 2; ++blk) {
        MambaP P = blk ? p2 : p1;

        // ---- LayerNorm: thread (l = t>>2, q = t&3), width-4 shuffle reduce
        {
            int l = t >> 2, q = t & 3;
            float4 xv[4];
            const float4* xr = (const float4*)(&X[l][q * 16]);
#pragma unroll
            for (int j = 0; j < 4; ++j) xv[j] = xr[j];
            float s = 0.f;
#pragma unroll
            for (int j = 0; j < 4; ++j) s += (xv[j].x + xv[j].y) + (xv[j].z + xv[j].w);
            s += __shfl_xor(s, 1, 4);
            s += __shfl_xor(s, 2, 4);
            float m = s * (1.f / 64.f);
            float v = 0.f;
#pragma unroll
            for (int j = 0; j < 4; ++j) {
                float dx;
                dx = xv[j].x - m; v = fmaf(dx, dx, v);
                dx = xv[j].y - m; v = fmaf(dx, dx, v);
                dx = xv[j].z - m; v = fmaf(dx, dx, v);
                dx = xv[j].w - m; v = fmaf(dx, dx, v);
            }
            v += __shfl_xor(v, 1, 4);
            v += __shfl_xor(v, 2, 4);
            float rstd = rsqrtf(v * (1.f / 64.f) + 1e-5f);
            const float4* g4 = (const float4*)(P.lng + q * 16);
            const float4* bb4 = (const float4*)(P.lnb + q * 16);
            float4* xw = (float4*)(&X[l][q * 16]);
#pragma unroll
            for (int j = 0; j < 4; ++j) {
                float4 g = g4[j], bb = bb4[j], o;
                o.x = (xv[j].x - m) * rstd * g.x + bb.x;
                o.y = (xv[j].y - m) * rstd * g.y + bb.y;
                o.z = (xv[j].z - m) * rstd * g.z + bb.z;
                o.w = (xv[j].w - m) * rstd * g.w + bb.w;
                xw[j] = o;
            }
        }
        __syncthreads();

        // ---- in-projection: e<64 -> XI (xi), e>=64 -> Yb (z). Weights hoisted to regs.
        {
            int e = t & 127, half = t >> 7;
            const float4* w4p = (const float4*)(P.inw + e * 64);
            float4 W[16];
#pragma unroll
            for (int k4 = 0; k4 < 16; ++k4) W[k4] = w4p[k4];
            float* dst = (e < 64) ? &XI[0][e] : &Yb[0][e - 64];
#pragma unroll 2
            for (int i = 0; i < 32; ++i) {
                int l = half * 32 + i;
                const float4* xr = (const float4*)(&X[l][0]);
                float a0 = 0.f, a1 = 0.f, a2 = 0.f, a3 = 0.f;
#pragma unroll
                for (int k4 = 0; k4 < 16; ++k4) {
                    float4 xv = xr[k4];
                    a0 = fmaf(xv.x, W[k4].x, a0);
                    a1 = fmaf(xv.y, W[k4].y, a1);
                    a2 = fmaf(xv.z, W[k4].z, a2);
                    a3 = fmaf(xv.w, W[k4].w, a3);
                }
                dst[l * 68] = (a0 + a1) + (a2 + a3);
            }
        }
        __syncthreads();

        // ---- causal depthwise conv(k=2)+silu: no output dependence -> fully parallel
        {
            int d = t & 63, lg = t >> 6;
            int l0 = lg * 16;
            float cur[16];
            float prev = (l0 == 0) ? 0.f : XI[l0 - 1][d];
#pragma unroll
            for (int j = 0; j < 16; ++j) cur[j] = XI[l0 + j][d];
            __syncthreads();
            float w0 = P.cvw[d * 2], w1 = P.cvw[d * 2 + 1], cb = P.cvb[d];
#pragma unroll
            for (int j = 0; j < 16; ++j) {
                float xp = (j == 0) ? prev : cur[j - 1];
                float v = fmaf(w0, xp, fmaf(w1, cur[j], cb));
                XI[l0 + j][d] = v / (1.f + __expf(-v));
            }
        }
        __syncthreads();

        // ---- x_dbl = u @ xpw^T : row hoisted to regs, 3 outputs per thread
        {
            int l = t & 63, jg = t >> 6;
            float4 xrow[16];
            const float4* xr = (const float4*)(&XI[l][0]);
#pragma unroll
            for (int k4 = 0; k4 < 16; ++k4) xrow[k4] = xr[k4];
#pragma unroll
            for (int jj = 0; jj < 3; ++jj) {
                int j = jg * 3 + jj;
                const float4* wr = (const float4*)(P.xpw + j * 64);
                float a0 = 0.f, a1 = 0.f, a2 = 0.f, a3 = 0.f;
#pragma unroll
                for (int k4 = 0; k4 < 16; ++k4) {
                    float4 wv = wr[k4];
                    a0 = fmaf(xrow[k4].x, wv.x, a0);
                    a1 = fmaf(xrow[k4].y, wv.y, a1);
                    a2 = fmaf(xrow[k4].z, wv.z, a2);
                    a3 = fmaf(xrow[k4].w, wv.w, a3);
                }
                float acc = (a0 + a1) + (a2 + a3);
                if (j < 4) dtr[l][j] = acc;
                else if (j < 8) Bm[l][j - 4] = acc;
                else Cm[l][j - 8] = acc;
            }
        }
        __syncthreads();

        // ---- precompute softplus(dt) for all (l,d), transposed store
        {
            int l = t & 63, dg = t >> 6;
            float d0 = dtr[l][0], d1 = dtr[l][1], d2 = dtr[l][2], d3 = dtr[l][3];
#pragma unroll 4
            for (int jj = 0; jj < 16; ++jj) {
                int d = dg * 16 + jj;
                const float4 wv = *(const float4*)(P.dtw + d * 4);
                float x = fmaf(wv.x, d0, fmaf(wv.y, d1, fmaf(wv.z, d2, fmaf(wv.w, d3, P.dtb[d]))));
                float sp = fmaxf(x, 0.f) + __logf(1.f + __expf(-fabsf(x)));
                DT[d][l] = sp;
            }
        }
        __syncthreads();

        // ---- selective scan: thread = (d = t>>2, n = t&3)
        {
            int d = t >> 2, n = t & 3;
            float Aval = -__expf(P.al[d * 4 + n]);
            float dpv = P.dp[d];
            const float* dtrow = &DT[d][0];
            float h = 0.f;
            for (int l = 0; l < 64; ++l) {
                float dtv = dtrow[l];
                float dA = __expf(dtv * Aval);
                float uv = XI[l][d];
                h = fmaf(dA, h, dtv * Bm[l][n] * uv);
                float part = h * Cm[l][n];
                part += __shfl_xor(part, 1, 4);
                part += __shfl_xor(part, 2, 4);
                if (n == 0) {
                    float zv = Yb[l][d];               // z parked here by in-proj
                    float yv = part + dpv * uv;
                    Yb[l][d] = yv * (zv / (1.f + __expf(-zv)));
                }
            }
        }
        __syncthreads();

        // ---- out-projection: weights hoisted, rows from LDS as float4
        {
            int eo = t & 63, lg = t >> 6;
            const float4* wp = (const float4*)(P.ow + eo * 64);
            float4 W[16];
#pragma unroll
            for (int k4 = 0; k4 < 16; ++k4) W[k4] = wp[k4];
#pragma unroll 2
            for (int ii = 0; ii < 16; ++ii) {
                int l = lg * 16 + ii;
                const float4* yr = (const float4*)(&Yb[l][0]);
                float a0 = 0.f, a1 = 0.f, a2 = 0.f, a3 = 0.f;
#pragma unroll
                for (int k4 = 0; k4 < 16; ++k4) {
                    float4 yv = yr[k4];
                    a0 = fmaf(yv.x, W[k4].x, a0);
                    a1 = fmaf(yv.y, W[k4].y, a1);
                    a2 = fmaf(yv.z, W[k4].z, a2);
                    a3 = fmaf(yv.w, W[k4].w, a3);
                }
                float acc = (a0 + a1) + (a2 + a3);
                if (blk == 0) X[l][eo] = acc;
                else out[b * 4096 + l * 64 + eo] = acc;
            }
        }
        __syncthreads();
    }
}

extern "C" void kernel_launch(void* const* d_in, const int* in_sizes, int n_in,
                              void* d_out, int out_size, void* d_ws, size_t ws_size,
                              hipStream_t stream) {
    const float* x   = (const float*)d_in[0];
    const float* c1w = (const float*)d_in[1];
    const float* c1b = (const float*)d_in[2];
    const float* c2w = (const float*)d_in[3];
    const float* c2b = (const float*)d_in[4];
    const float* c3w = (const float*)d_in[5];
    const float* c3b = (const float*)d_in[6];
    const float* lw  = (const float*)d_in[7];
    const float* lb  = (const float*)d_in[8];

    MambaP p1, p2;
    p1.lng = (const float*)d_in[9];  p1.lnb = (const float*)d_in[10];
    p1.inw = (const float*)d_in[11]; p1.cvw = (const float*)d_in[12];
    p1.cvb = (const float*)d_in[13]; p1.xpw = (const float*)d_in[14];
    p1.dtw = (const float*)d_in[15]; p1.dtb = (const float*)d_in[16];
    p1.al  = (const float*)d_in[17]; p1.dp  = (const float*)d_in[18];
    p1.ow  = (const float*)d_in[19];
    p2.lng = (const float*)d_in[20]; p2.lnb = (const float*)d_in[21];
    p2.inw = (const float*)d_in[22]; p2.cvw = (const float*)d_in[23];
    p2.cvb = (const float*)d_in[24]; p2.xpw = (const float*)d_in[25];
    p2.dtw = (const float*)d_in[26]; p2.dtb = (const float*)d_in[27];
    p2.al  = (const float*)d_in[28]; p2.dp  = (const float*)d_in[29];
    p2.ow  = (const float*)d_in[30];

    char* base = (char*)d_ws;
    float* h1 = (float*)base;                                   // [0, 64 MiB)
    float* h2 = (float*)(base + (size_t)64 * 1024 * 1024);      // [64, 128 MiB)
    __hip_bfloat16* lwb = (__hip_bfloat16*)base;                        // [0, 16 MiB)
    __hip_bfloat16* h3b = (__hip_bfloat16*)(base + (size_t)16 * 1024 * 1024);  // [16, 18 MiB)
    float* lin = (float*)(base + (size_t)18 * 1024 * 1024);             // [18, 26 MiB)
    float* outp = (float*)d_out;

    conv1_pool<<<dim3(NB), dim3(256), 0, stream>>>(x, c1w, c1b, h1);
    conv2_pool<<<dim3(8, NB), dim3(256), 0, stream>>>(h1, c2w, c2b, h2);
    lw_to_bf16<<<dim3(8192), dim3(256), 0, stream>>>((const float4*)lw, (ushort4*)lwb);
    conv3_pool<<<dim3(4, NB), dim3(256), 0, stream>>>(h2, c3w, c3b, h3b);
    lin_gemm_mfma<<<dim3(32, 8), dim3(256), 0, stream>>>(h3b, lwb, lb, lin);
    mamba2_kernel<<<dim3(NB), dim3(256), 0, stream>>>(lin, p1, p2, outp);
}

// Round 5
// 356.397 us; speedup vs baseline: 5.8020x; 1.4287x over previous
//
#include <hip/hip_runtime.h>
#include <hip/hip_bf16.h>
#include <math.h>

#define NB 512

typedef __attribute__((ext_vector_type(8))) short short8;
typedef __attribute__((ext_vector_type(4))) float f32x4;
union U4 { uint4 u; short8 s8; };

__device__ __forceinline__ int swz(int u) { return u ^ ((u >> 3) & 7); }

// ---------------- conv1: [B,1,4096] -> conv(k5,pad2)+relu+maxpool2 -> h1t[B][2048][16] bf16
__global__ __launch_bounds__(256) void conv1_pool_t(const float* __restrict__ x,
                                                    const float* __restrict__ w,
                                                    const float* __restrict__ bias,
                                                    __hip_bfloat16* __restrict__ h1t) {
    __shared__ float xs[4100];   // [pad2 | 4096 | pad2]
    int t = threadIdx.x, b = blockIdx.x;
    const float4* xb4 = (const float4*)(x + b * 4096);
    for (int i = t; i < 1024; i += 256) {
        float4 v = xb4[i];
        float* d = xs + 2 + i * 4;
        d[0] = v.x; d[1] = v.y; d[2] = v.z; d[3] = v.w;
    }
    if (t == 0) { xs[0] = xs[1] = 0.f; xs[4098] = xs[4099] = 0.f; }
    __syncthreads();
    // uniform weights -> scalar regs
    float wv[80], bv[16];
#pragma unroll
    for (int i = 0; i < 80; ++i) wv[i] = w[i];
#pragma unroll
    for (int i = 0; i < 16; ++i) bv[i] = bias[i];
    for (int chunk = 0; chunk < 8; ++chunk) {
        int pos = chunk * 256 + t;
        const float* s = xs + 2 * pos;
        float s0 = s[0], s1 = s[1], s2 = s[2], s3 = s[3], s4 = s[4], s5 = s[5];
        union { uint4 q[2]; __hip_bfloat16 h[16]; } o;
#pragma unroll
        for (int c = 0; c < 16; ++c) {
            const float* wr = wv + c * 5;
            float v0 = fmaf(wr[0], s0, fmaf(wr[1], s1, fmaf(wr[2], s2, fmaf(wr[3], s3, fmaf(wr[4], s4, bv[c])))));
            float v1 = fmaf(wr[0], s1, fmaf(wr[1], s2, fmaf(wr[2], s3, fmaf(wr[3], s4, fmaf(wr[4], s5, bv[c])))));
            o.h[c] = __float2bfloat16(fmaxf(fmaxf(v0, v1), 0.f));
        }
        uint4* dst = (uint4*)(h1t + (size_t)b * 32768 + pos * 16);
        dst[0] = o.q[0]; dst[1] = o.q[1];
    }
}

// ---------------- prep: lw->bf16 (blocks 0..8191) + w2b/w3b reorg (block 8192)
__global__ __launch_bounds__(256) void prep_kernel(const float4* __restrict__ lw4,
                                                   ushort4* __restrict__ lwb4,
                                                   const float* __restrict__ w2,
                                                   __hip_bfloat16* __restrict__ w2b,
                                                   const float* __restrict__ w3,
                                                   __hip_bfloat16* __restrict__ w3b) {
    int blk = blockIdx.x, t = threadIdx.x;
    if (blk < 8192) {
        int i = blk * 256 + t;
        float4 v = lw4[i];
        union { ushort4 u; __hip_bfloat16 h[4]; } o;
        o.h[0] = __float2bfloat16(v.x);
        o.h[1] = __float2bfloat16(v.y);
        o.h[2] = __float2bfloat16(v.z);
        o.h[3] = __float2bfloat16(v.w);
        lwb4[i] = o.u;
    } else {
        // w2b[c2][tp*32 + tl*16 + c1] = (tap=2tp+tl)<5 ? w2[c2*80 + c1*5 + tap] : 0
        for (int i = t; i < 3072; i += 256) {
            int c2 = i / 96, rest = i - c2 * 96;
            int tp = rest >> 5, r2 = rest & 31;
            int tl = r2 >> 4, c1 = r2 & 15;
            int tap = tp * 2 + tl;
            float v = (tap < 5) ? w2[c2 * 80 + c1 * 5 + tap] : 0.f;
            w2b[i] = __float2bfloat16(v);
        }
        // w3b[c3][kk*32 + c1] = w3[c3*160 + c1*5 + kk]
        for (int i = t; i < 10240; i += 256) {
            int c3 = i / 160, rest = i - c3 * 160;
            int kk = rest >> 5, c1 = rest & 31;
            w3b[i] = __float2bfloat16(w3[c3 * 160 + c1 * 5 + kk]);
        }
    }
}

// ---------------- conv2 MFMA: h1t[B][2048][16] -> conv(k5)+maxpool2+relu -> h2t[B][1024][32]
__global__ __launch_bounds__(256) void conv2_mfma(const __hip_bfloat16* __restrict__ h1t,
                                                  const __hip_bfloat16* __restrict__ w2b,
                                                  const float* __restrict__ bias,
                                                  __hip_bfloat16* __restrict__ h2t) {
    __shared__ uint4 IN[4120];   // rows r=0..2053 (input pos r-2), 2 units/row, swizzled
    int t = threadIdx.x, b = blockIdx.x;
    const uint4* src = (const uint4*)(h1t + (size_t)b * 32768);
    if (t < 12) {
        int u = (t < 4) ? t : (4096 + t);   // units 0..3 and 4100..4107
        IN[swz(u)] = (uint4){0, 0, 0, 0};
    }
    for (int i = t; i < 4096; i += 256) IN[swz(4 + i)] = src[i];

    int lane = t & 63, w = t >> 6;
    int m = lane & 15, quad = lane >> 4;
    U4 Bf[3][2];
    const uint4* wsrc = (const uint4*)w2b;
#pragma unroll
    for (int ct = 0; ct < 2; ++ct)
#pragma unroll
        for (int tp = 0; tp < 3; ++tp)
            Bf[tp][ct].u = wsrc[(ct * 16 + m) * 12 + tp * 4 + quad];
    float bv[2];
#pragma unroll
    for (int ct = 0; ct < 2; ++ct) bv[ct] = bias[ct * 16 + m];
    __syncthreads();

    __hip_bfloat16* outb = h2t + (size_t)b * 32768;
    for (int i = 0; i < 32; ++i) {
        int p = w * 32 + i;
        f32x4 acc[2];
#pragma unroll
        for (int ct = 0; ct < 2; ++ct) acc[ct] = (f32x4){bv[ct], bv[ct], bv[ct], bv[ct]};
#pragma unroll
        for (int tp = 0; tp < 3; ++tp) {
            int u = 2 * (p * 16 + m + 2 * tp) + quad;
            U4 av; av.u = IN[swz(u)];
            acc[0] = __builtin_amdgcn_mfma_f32_16x16x32_bf16(av.s8, Bf[tp][0].s8, acc[0], 0, 0, 0);
            acc[1] = __builtin_amdgcn_mfma_f32_16x16x32_bf16(av.s8, Bf[tp][1].s8, acc[1], 0, 0, 0);
        }
        int pp = p * 8 + quad * 2;
#pragma unroll
        for (int ct = 0; ct < 2; ++ct) {
            float o0 = fmaxf(fmaxf(acc[ct][0], acc[ct][1]), 0.f);
            float o1 = fmaxf(fmaxf(acc[ct][2], acc[ct][3]), 0.f);
            outb[pp * 32 + ct * 16 + m] = __float2bfloat16(o0);
            outb[(pp + 1) * 32 + ct * 16 + m] = __float2bfloat16(o1);
        }
    }
}

// ---------------- conv3 MFMA + relu + avgpool(32): h2t[B][1024][32] -> h3b[B][2048]
__global__ __launch_bounds__(256) void conv3_mfma(const __hip_bfloat16* __restrict__ h2t,
                                                  const __hip_bfloat16* __restrict__ w3b,
                                                  const float* __restrict__ bias,
                                                  __hip_bfloat16* __restrict__ h3b) {
    __shared__ uint4 IN[4120];   // rows r=0..1027 (input pos r-2), 4 units/row, swizzled
    int t = threadIdx.x, b = blockIdx.x;
    const uint4* src = (const uint4*)(h2t + (size_t)b * 32768);
    if (t < 16) {
        int u = (t < 8) ? t : (4096 + t);   // units 0..7 and 4104..4111
        IN[swz(u)] = (uint4){0, 0, 0, 0};
    }
    for (int i = t; i < 4096; i += 256) IN[swz(8 + i)] = src[i];

    int lane = t & 63, w = t >> 6;
    int m = lane & 15, quad = lane >> 4;
    U4 Bf[5][4];
    const uint4* wsrc = (const uint4*)w3b;
#pragma unroll
    for (int ct = 0; ct < 4; ++ct)
#pragma unroll
        for (int kk = 0; kk < 5; ++kk)
            Bf[kk][ct].u = wsrc[(ct * 16 + m) * 20 + kk * 4 + quad];
    float bv[4];
#pragma unroll
    for (int ct = 0; ct < 4; ++ct) bv[ct] = bias[ct * 16 + m];
    __syncthreads();

    for (int ii = 0; ii < 8; ++ii) {
        float sum[4] = {0.f, 0.f, 0.f, 0.f};
#pragma unroll
        for (int half = 0; half < 2; ++half) {
            int p = w * 16 + ii * 2 + half;
            f32x4 acc[4];
#pragma unroll
            for (int ct = 0; ct < 4; ++ct) acc[ct] = (f32x4){bv[ct], bv[ct], bv[ct], bv[ct]};
#pragma unroll
            for (int kk = 0; kk < 5; ++kk) {
                int u = 4 * (p * 16 + m + kk) + quad;
                U4 av; av.u = IN[swz(u)];
#pragma unroll
                for (int ct = 0; ct < 4; ++ct)
                    acc[ct] = __builtin_amdgcn_mfma_f32_16x16x32_bf16(av.s8, Bf[kk][ct].s8, acc[ct], 0, 0, 0);
            }
#pragma unroll
            for (int ct = 0; ct < 4; ++ct) {
                sum[ct] += fmaxf(acc[ct][0], 0.f) + fmaxf(acc[ct][1], 0.f)
                         + fmaxf(acc[ct][2], 0.f) + fmaxf(acc[ct][3], 0.f);
            }
        }
#pragma unroll
        for (int ct = 0; ct < 4; ++ct) {
            float s = sum[ct];
            s += __shfl_xor(s, 16, 64);
            s += __shfl_xor(s, 32, 64);
            sum[ct] = s;
        }
        float sv = (quad == 0) ? sum[0] : (quad == 1) ? sum[1] : (quad == 2) ? sum[2] : sum[3];
        int win = w * 8 + ii;
        h3b[b * 2048 + (quad * 16 + m) * 32 + win] = __float2bfloat16(sv * (1.f / 32.f));
    }
}

// ---------------- MFMA GEMM: C[512,4096] = A[512,2048]bf16 @ B[4096,2048]bf16^T + lb
__global__ __launch_bounds__(256) void lin_gemm_mfma(const __hip_bfloat16* __restrict__ A,
                                                     const __hip_bfloat16* __restrict__ B,
                                                     const float* __restrict__ bias,
                                                     float* __restrict__ C) {
    __shared__ uint4 A_s[64 * 8];
    __shared__ uint4 B_s[128 * 8];
    int t = threadIdx.x;
    int col0 = blockIdx.x * 128;
    int row0 = blockIdx.y * 64;
    int w = t >> 6, lane = t & 63;
    int m = lane & 15, quad = lane >> 4;

    f32x4 acc[8];
#pragma unroll
    for (int nt = 0; nt < 8; ++nt) acc[nt] = (f32x4){0.f, 0.f, 0.f, 0.f};

    for (int ki = 0; ki < 32; ++ki) {
        int k0 = ki * 64;
#pragma unroll
        for (int p = 0; p < 2; ++p) {
            int id = p * 256 + t;
            int r = id >> 3, u = id & 7;
            A_s[r * 8 + (u ^ (r & 7))] = *(const uint4*)(A + (row0 + r) * 2048 + k0 + u * 8);
        }
#pragma unroll
        for (int p = 0; p < 4; ++p) {
            int id = p * 256 + t;
            int r = id >> 3, u = id & 7;
            B_s[r * 8 + (u ^ (r & 7))] = *(const uint4*)(B + (col0 + r) * 2048 + k0 + u * 8);
        }
        __syncthreads();
#pragma unroll
        for (int c = 0; c < 2; ++c) {
            int ra = w * 16 + m;
            int ua = c * 4 + quad;
            U4 av; av.u = A_s[ra * 8 + (ua ^ (ra & 7))];
#pragma unroll
            for (int nt = 0; nt < 8; ++nt) {
                int rb = nt * 16 + m;
                U4 bv; bv.u = B_s[rb * 8 + (ua ^ (rb & 7))];
                acc[nt] = __builtin_amdgcn_mfma_f32_16x16x32_bf16(av.s8, bv.s8, acc[nt], 0, 0, 0);
            }
        }
        __syncthreads();
    }
#pragma unroll
    for (int nt = 0; nt < 8; ++nt) {
        int col = col0 + nt * 16 + m;
        float bv = bias[col];
#pragma unroll
        for (int reg = 0; reg < 4; ++reg) {
            int row = row0 + w * 16 + quad * 4 + reg;
            C[row * 4096 + col] = acc[nt][reg] + bv;
        }
    }
}

// ---------------- fused double {layernorm + mamba}: [B,64,64] -> [B,64,64]
struct MambaP {
    const float *lng, *lnb, *inw, *cvw, *cvb, *xpw, *dtw, *dtb, *al, *dp, *ow;
};

__global__ __launch_bounds__(256, 2) void mamba2_kernel(const float* __restrict__ lin,
                                                        MambaP p1, MambaP p2,
                                                        float* __restrict__ out) {
    __shared__ float X[64][68];
    __shared__ float XI[64][68];
    __shared__ float Yb[64][68];
    __shared__ float DT[64][68];
    __shared__ float dtr[64][5];
    __shared__ float Bm[64][4], Cm[64][4];
    int b = blockIdx.x, t = threadIdx.x;

    {
        const float4* lin4 = (const float4*)(lin + b * 4096);
        for (int i = t; i < 1024; i += 256) {
            float4 v = lin4[i];
            *(float4*)(&X[i >> 4][(i & 15) * 4]) = v;
        }
    }
    __syncthreads();

    for (int blk = 0; blk < 2; ++blk) {
        MambaP P = blk ? p2 : p1;

        {
            int l = t >> 2, q = t & 3;
            float4 xv[4];
            const float4* xr = (const float4*)(&X[l][q * 16]);
#pragma unroll
            for (int j = 0; j < 4; ++j) xv[j] = xr[j];
            float s = 0.f;
#pragma unroll
            for (int j = 0; j < 4; ++j) s += (xv[j].x + xv[j].y) + (xv[j].z + xv[j].w);
            s += __shfl_xor(s, 1, 4);
            s += __shfl_xor(s, 2, 4);
            float m = s * (1.f / 64.f);
            float v = 0.f;
#pragma unroll
            for (int j = 0; j < 4; ++j) {
                float dx;
                dx = xv[j].x - m; v = fmaf(dx, dx, v);
                dx = xv[j].y - m; v = fmaf(dx, dx, v);
                dx = xv[j].z - m; v = fmaf(dx, dx, v);
                dx = xv[j].w - m; v = fmaf(dx, dx, v);
            }
            v += __shfl_xor(v, 1, 4);
            v += __shfl_xor(v, 2, 4);
            float rstd = rsqrtf(v * (1.f / 64.f) + 1e-5f);
            const float4* g4 = (const float4*)(P.lng + q * 16);
            const float4* bb4 = (const float4*)(P.lnb + q * 16);
            float4* xw = (float4*)(&X[l][q * 16]);
#pragma unroll
            for (int j = 0; j < 4; ++j) {
                float4 g = g4[j], bb = bb4[j], o;
                o.x = (xv[j].x - m) * rstd * g.x + bb.x;
                o.y = (xv[j].y - m) * rstd * g.y + bb.y;
                o.z = (xv[j].z - m) * rstd * g.z + bb.z;
                o.w = (xv[j].w - m) * rstd * g.w + bb.w;
                xw[j] = o;
            }
        }
        __syncthreads();

        {
            int e = t & 127, half = t >> 7;
            const float4* w4p = (const float4*)(P.inw + e * 64);
            float4 W[16];
#pragma unroll
            for (int k4 = 0; k4 < 16; ++k4) W[k4] = w4p[k4];
            float* dst = (e < 64) ? &XI[0][e] : &Yb[0][e - 64];
#pragma unroll 2
            for (int i = 0; i < 32; ++i) {
                int l = half * 32 + i;
                const float4* xr = (const float4*)(&X[l][0]);
                float a0 = 0.f, a1 = 0.f, a2 = 0.f, a3 = 0.f;
#pragma unroll
                for (int k4 = 0; k4 < 16; ++k4) {
                    float4 xv = xr[k4];
                    a0 = fmaf(xv.x, W[k4].x, a0);
                    a1 = fmaf(xv.y, W[k4].y, a1);
                    a2 = fmaf(xv.z, W[k4].z, a2);
                    a3 = fmaf(xv.w, W[k4].w, a3);
                }
                dst[l * 68] = (a0 + a1) + (a2 + a3);
            }
        }
        __syncthreads();

        {
            int d = t & 63, lg = t >> 6;
            int l0 = lg * 16;
            float cur[16];
            float prev = (l0 == 0) ? 0.f : XI[l0 - 1][d];
#pragma unroll
            for (int j = 0; j < 16; ++j) cur[j] = XI[l0 + j][d];
            __syncthreads();
            float w0 = P.cvw[d * 2], w1 = P.cvw[d * 2 + 1], cb = P.cvb[d];
#pragma unroll
            for (int j = 0; j < 16; ++j) {
                float xp = (j == 0) ? prev : cur[j - 1];
                float v = fmaf(w0, xp, fmaf(w1, cur[j], cb));
                XI[l0 + j][d] = v / (1.f + __expf(-v));
            }
        }
        __syncthreads();

        {
            int l = t & 63, jg = t >> 6;
            float4 xrow[16];
            const float4* xr = (const float4*)(&XI[l][0]);
#pragma unroll
            for (int k4 = 0; k4 < 16; ++k4) xrow[k4] = xr[k4];
#pragma unroll
            for (int jj = 0; jj < 3; ++jj) {
                int j = jg * 3 + jj;
                const float4* wr = (const float4*)(P.xpw + j * 64);
                float a0 = 0.f, a1 = 0.f, a2 = 0.f, a3 = 0.f;
#pragma unroll
                for (int k4 = 0; k4 < 16; ++k4) {
                    float4 wv = wr[k4];
                    a0 = fmaf(xrow[k4].x, wv.x, a0);
                    a1 = fmaf(xrow[k4].y, wv.y, a1);
                    a2 = fmaf(xrow[k4].z, wv.z, a2);
                    a3 = fmaf(xrow[k4].w, wv.w, a3);
                }
                float acc = (a0 + a1) + (a2 + a3);
                if (j < 4) dtr[l][j] = acc;
                else if (j < 8) Bm[l][j - 4] = acc;
                else Cm[l][j - 8] = acc;
            }
        }
        __syncthreads();

        {
            int l = t & 63, dg = t >> 6;
            float d0 = dtr[l][0], d1 = dtr[l][1], d2 = dtr[l][2], d3 = dtr[l][3];
#pragma unroll 4
            for (int jj = 0; jj < 16; ++jj) {
                int d = dg * 16 + jj;
                const float4 wv = *(const float4*)(P.dtw + d * 4);
                float x = fmaf(wv.x, d0, fmaf(wv.y, d1, fmaf(wv.z, d2, fmaf(wv.w, d3, P.dtb[d]))));
                float sp = fmaxf(x, 0.f) + __logf(1.f + __expf(-fabsf(x)));
                DT[d][l] = sp;
            }
        }
        __syncthreads();

        {
            int d = t >> 2, n = t & 3;
            float Aval = -__expf(P.al[d * 4 + n]);
            float dpv = P.dp[d];
            const float* dtrow = &DT[d][0];
            float h = 0.f;
            for (int l = 0; l < 64; ++l) {
                float dtv = dtrow[l];
                float dA = __expf(dtv * Aval);
                float uv = XI[l][d];
                h = fmaf(dA, h, dtv * Bm[l][n] * uv);
                float part = h * Cm[l][n];
                part += __shfl_xor(part, 1, 4);
                part += __shfl_xor(part, 2, 4);
                if (n == 0) {
                    float zv = Yb[l][d];
                    float yv = part + dpv * uv;
                    Yb[l][d] = yv * (zv / (1.f + __expf(-zv)));
                }
            }
        }
        __syncthreads();

        {
            int eo = t & 63, lg = t >> 6;
            const float4* wp = (const float4*)(P.ow + eo * 64);
            float4 W[16];
#pragma unroll
            for (int k4 = 0; k4 < 16; ++k4) W[k4] = wp[k4];
#pragma unroll 2
            for (int ii = 0; ii < 16; ++ii) {
                int l = lg * 16 + ii;
                const float4* yr = (const float4*)(&Yb[l][0]);
                float a0 = 0.f, a1 = 0.f, a2 = 0.f, a3 = 0.f;
#pragma unroll
                for (int k4 = 0; k4 < 16; ++k4) {
                    float4 yv = yr[k4];
                    a0 = fmaf(yv.x, W[k4].x, a0);
                    a1 = fmaf(yv.y, W[k4].y, a1);
                    a2 = fmaf(yv.z, W[k4].z, a2);
                    a3 = fmaf(yv.w, W[k4].w, a3);
                }
                float acc = (a0 + a1) + (a2 + a3);
                if (blk == 0) X[l][eo] = acc;
                else out[b * 4096 + l * 64 + eo] = acc;
            }
        }
        __syncthreads();
    }
}

extern "C" void kernel_launch(void* const* d_in, const int* in_sizes, int n_in,
                              void* d_out, int out_size, void* d_ws, size_t ws_size,
                              hipStream_t stream) {
    const float* x   = (const float*)d_in[0];
    const float* c1w = (const float*)d_in[1];
    const float* c1b = (const float*)d_in[2];
    const float* c2w = (const float*)d_in[3];
    const float* c2b = (const float*)d_in[4];
    const float* c3w = (const float*)d_in[5];
    const float* c3b = (const float*)d_in[6];
    const float* lw  = (const float*)d_in[7];
    const float* lb  = (const float*)d_in[8];

    MambaP p1, p2;
    p1.lng = (const float*)d_in[9];  p1.lnb = (const float*)d_in[10];
    p1.inw = (const float*)d_in[11]; p1.cvw = (const float*)d_in[12];
    p1.cvb = (const float*)d_in[13]; p1.xpw = (const float*)d_in[14];
    p1.dtw = (const float*)d_in[15]; p1.dtb = (const float*)d_in[16];
    p1.al  = (const float*)d_in[17]; p1.dp  = (const float*)d_in[18];
    p1.ow  = (const float*)d_in[19];
    p2.lng = (const float*)d_in[20]; p2.lnb = (const float*)d_in[21];
    p2.inw = (const float*)d_in[22]; p2.cvw = (const float*)d_in[23];
    p2.cvb = (const float*)d_in[24]; p2.xpw = (const float*)d_in[25];
    p2.dtw = (const float*)d_in[26]; p2.dtb = (const float*)d_in[27];
    p2.al  = (const float*)d_in[28]; p2.dp  = (const float*)d_in[29];
    p2.ow  = (const float*)d_in[30];

    const size_t MB = 1024 * 1024;
    char* base = (char*)d_ws;
    __hip_bfloat16* h1t = (__hip_bfloat16*)base;                    // [0, 32M)
    __hip_bfloat16* h2t = (__hip_bfloat16*)(base + 32 * MB);        // [32M, 64M)
    __hip_bfloat16* lwb = (__hip_bfloat16*)(base + 64 * MB);        // [64M, 80M)
    __hip_bfloat16* h3b = (__hip_bfloat16*)(base + 80 * MB);        // [80M, 82M)
    float* lin          = (float*)(base + 82 * MB);                 // [82M, 90M)
    __hip_bfloat16* w2b = (__hip_bfloat16*)(base + 90 * MB);        // 6 KB
    __hip_bfloat16* w3b = (__hip_bfloat16*)(base + 90 * MB + 65536);// 20 KB
    float* outp = (float*)d_out;

    conv1_pool_t<<<dim3(NB), dim3(256), 0, stream>>>(x, c1w, c1b, h1t);
    prep_kernel<<<dim3(8193), dim3(256), 0, stream>>>((const float4*)lw, (ushort4*)lwb,
                                                      c2w, w2b, c3w, w3b);
    conv2_mfma<<<dim3(NB), dim3(256), 0, stream>>>(h1t, w2b, c2b, h2t);
    conv3_mfma<<<dim3(NB), dim3(256), 0, stream>>>(h2t, w3b, c3b, h3b);
    lin_gemm_mfma<<<dim3(32, 8), dim3(256), 0, stream>>>(h3b, lwb, lb, lin);
    mamba2_kernel<<<dim3(NB), dim3(256), 0, stream>>>(lin, p1, p2, outp);
}

// Round 6
// 351.496 us; speedup vs baseline: 5.8829x; 1.0139x over previous
//
#include <hip/hip_runtime.h>
#include <hip/hip_bf16.h>
#include <math.h>

#define NB 512

typedef __attribute__((ext_vector_type(8))) short short8;
typedef __attribute__((ext_vector_type(4))) float f32x4;
union U4 { uint4 u; short8 s8; };

__device__ __forceinline__ int swz(int u) { return u ^ ((u >> 3) & 7); }

// ---------------- prep: reorg conv2/conv3 weights to MFMA B-fragment layout (bf16)
__global__ __launch_bounds__(256) void prep_w(const float* __restrict__ w2,
                                              __hip_bfloat16* __restrict__ w2b,
                                              const float* __restrict__ w3,
                                              __hip_bfloat16* __restrict__ w3b) {
    int i = blockIdx.x * 256 + threadIdx.x;   // 52 blocks * 256 = 13312
    if (i < 3072) {
        // w2b[c2][tp*32 + tl*16 + c1] = (tap=2tp+tl)<5 ? w2[c2*80 + c1*5 + tap] : 0
        int c2 = i / 96, rest = i - c2 * 96;
        int tp = rest >> 5, r2 = rest & 31;
        int tl = r2 >> 4, c1 = r2 & 15;
        int tap = tp * 2 + tl;
        float v = (tap < 5) ? w2[c2 * 80 + c1 * 5 + tap] : 0.f;
        w2b[i] = __float2bfloat16(v);
    } else {
        // w3b[c3][kk*32 + c1] = w3[c3*160 + c1*5 + kk]
        int j = i - 3072;   // < 10240
        int c3 = j / 160, rest = j - c3 * 160;
        int kk = rest >> 5, c1 = rest & 31;
        w3b[j] = __float2bfloat16(w3[c3 * 160 + c1 * 5 + kk]);
    }
}

// ---------------- fused conv trunk: x[B,4096] -> conv1+pool -> conv2+pool -> conv3+avgpool -> h3b[B,2048]
// one block per batch; h1/h2 intermediates live entirely in LDS
__global__ __launch_bounds__(256) void conv_trunk(const float* __restrict__ x,
                                                  const float* __restrict__ c1w,
                                                  const float* __restrict__ c1b,
                                                  const __hip_bfloat16* __restrict__ w2b,
                                                  const float* __restrict__ c2b,
                                                  const __hip_bfloat16* __restrict__ w3b,
                                                  const float* __restrict__ c3b,
                                                  __hip_bfloat16* __restrict__ h3b) {
    __shared__ uint4 H1[4120];   // conv1 out: pad2 rows | 2048 pos x 2 units (16ch bf16) | pads
    __shared__ uint4 H2[4120];   // conv2 out: pad2 rows | 1024 pos x 4 units (32ch bf16) | pads
    float* xs = (float*)H2;      // alias: raw input staged here during phase 1 only
    int t = threadIdx.x, b = blockIdx.x;
    int lane = t & 63, w = t >> 6;
    int m = lane & 15, quad = lane >> 4;

    // ---- phase 0: stage x
    const float4* xb4 = (const float4*)(x + b * 4096);
    for (int i = t; i < 1024; i += 256) {
        float4 v = xb4[i];
        float* d = xs + 2 + i * 4;
        d[0] = v.x; d[1] = v.y; d[2] = v.z; d[3] = v.w;
    }
    if (t == 0) { xs[0] = xs[1] = 0.f; xs[4098] = xs[4099] = 0.f; }
    // conv2 B-fragments (hoisted; overlaps with staging latency)
    U4 Bf2[3][2];
    {
        const uint4* wsrc = (const uint4*)w2b;
#pragma unroll
        for (int ct = 0; ct < 2; ++ct)
#pragma unroll
            for (int tp = 0; tp < 3; ++tp)
                Bf2[tp][ct].u = wsrc[(ct * 16 + m) * 12 + tp * 4 + quad];
    }
    float bv2[2];
#pragma unroll
    for (int ct = 0; ct < 2; ++ct) bv2[ct] = c2b[ct * 16 + m];
    // conv1 weights
    float wv[80], bv1[16];
#pragma unroll
    for (int i = 0; i < 80; ++i) wv[i] = c1w[i];
#pragma unroll
    for (int i = 0; i < 16; ++i) bv1[i] = c1b[i];
    __syncthreads();

    // ---- phase 1: conv1(k5)+maxpool2+relu -> H1 (bf16, position-major)
    if (t < 12) {
        int u = (t < 4) ? t : (4096 + t);   // units 0..3 and 4100..4107
        H1[swz(u)] = (uint4){0, 0, 0, 0};
    }
    for (int chunk = 0; chunk < 8; ++chunk) {
        int pos = chunk * 256 + t;
        const float* s = xs + 2 * pos;
        float s0 = s[0], s1 = s[1], s2 = s[2], s3 = s[3], s4 = s[4], s5 = s[5];
        union { uint4 q[2]; __hip_bfloat16 h[16]; } o;
#pragma unroll
        for (int c = 0; c < 16; ++c) {
            const float* wr = wv + c * 5;
            float v0 = fmaf(wr[0], s0, fmaf(wr[1], s1, fmaf(wr[2], s2, fmaf(wr[3], s3, fmaf(wr[4], s4, bv1[c])))));
            float v1 = fmaf(wr[0], s1, fmaf(wr[1], s2, fmaf(wr[2], s3, fmaf(wr[3], s4, fmaf(wr[4], s5, bv1[c])))));
            o.h[c] = __float2bfloat16(fmaxf(fmaxf(v0, v1), 0.f));
        }
        H1[swz(4 + pos * 2)] = o.q[0];
        H1[swz(4 + pos * 2 + 1)] = o.q[1];
    }
    __syncthreads();

    // ---- phase 2: conv2(k5)+maxpool2+relu MFMA -> H2 (bf16, position-major)
    if (t < 16) {
        int u = (t < 8) ? t : (4096 + t);   // units 0..7 and 4104..4111
        H2[swz(u)] = (uint4){0, 0, 0, 0};
    }
    __hip_bfloat16* H2h = (__hip_bfloat16*)H2;
    for (int i = 0; i < 32; ++i) {
        int p = w * 32 + i;                 // group of 16 output positions
        f32x4 acc[2];
#pragma unroll
        for (int ct = 0; ct < 2; ++ct) acc[ct] = (f32x4){bv2[ct], bv2[ct], bv2[ct], bv2[ct]};
#pragma unroll
        for (int tp = 0; tp < 3; ++tp) {
            int u = 2 * (p * 16 + m + 2 * tp) + quad;
            U4 av; av.u = H1[swz(u)];
            acc[0] = __builtin_amdgcn_mfma_f32_16x16x32_bf16(av.s8, Bf2[tp][0].s8, acc[0], 0, 0, 0);
            acc[1] = __builtin_amdgcn_mfma_f32_16x16x32_bf16(av.s8, Bf2[tp][1].s8, acc[1], 0, 0, 0);
        }
        int pp = p * 8 + quad * 2;
#pragma unroll
        for (int ct = 0; ct < 2; ++ct) {
            float o0 = fmaxf(fmaxf(acc[ct][0], acc[ct][1]), 0.f);
            float o1 = fmaxf(fmaxf(acc[ct][2], acc[ct][3]), 0.f);
            int ch = ct * 16 + m;
            int u0 = 8 + pp * 4 + (ch >> 3);
            H2h[swz(u0) * 8 + (ch & 7)] = __float2bfloat16(o0);
            H2h[swz(u0 + 4) * 8 + (ch & 7)] = __float2bfloat16(o1);
        }
    }
    __syncthreads();

    // ---- phase 3: conv3(k5)+relu+avgpool(32) MFMA -> h3b
    U4 Bf3[5][4];
    {
        const uint4* wsrc = (const uint4*)w3b;
#pragma unroll
        for (int ct = 0; ct < 4; ++ct)
#pragma unroll
            for (int kk = 0; kk < 5; ++kk)
                Bf3[kk][ct].u = wsrc[(ct * 16 + m) * 20 + kk * 4 + quad];
    }
    float bv3[4];
#pragma unroll
    for (int ct = 0; ct < 4; ++ct) bv3[ct] = c3b[ct * 16 + m];

    for (int ii = 0; ii < 8; ++ii) {
        float sum[4] = {0.f, 0.f, 0.f, 0.f};
#pragma unroll
        for (int half = 0; half < 2; ++half) {
            int p = w * 16 + ii * 2 + half;
            f32x4 acc[4];
#pragma unroll
            for (int ct = 0; ct < 4; ++ct) acc[ct] = (f32x4){bv3[ct], bv3[ct], bv3[ct], bv3[ct]};
#pragma unroll
            for (int kk = 0; kk < 5; ++kk) {
                int u = 4 * (p * 16 + m + kk) + quad;
                U4 av; av.u = H2[swz(u)];
#pragma unroll
                for (int ct = 0; ct < 4; ++ct)
                    acc[ct] = __builtin_amdgcn_mfma_f32_16x16x32_bf16(av.s8, Bf3[kk][ct].s8, acc[ct], 0, 0, 0);
            }
#pragma unroll
            for (int ct = 0; ct < 4; ++ct) {
                sum[ct] += fmaxf(acc[ct][0], 0.f) + fmaxf(acc[ct][1], 0.f)
                         + fmaxf(acc[ct][2], 0.f) + fmaxf(acc[ct][3], 0.f);
            }
        }
#pragma unroll
        for (int ct = 0; ct < 4; ++ct) {
            float s = sum[ct];
            s += __shfl_xor(s, 16, 64);
            s += __shfl_xor(s, 32, 64);
            sum[ct] = s;
        }
        float sv = (quad == 0) ? sum[0] : (quad == 1) ? sum[1] : (quad == 2) ? sum[2] : sum[3];
        int win = w * 8 + ii;
        h3b[b * 2048 + (quad * 16 + m) * 32 + win] = __float2bfloat16(sv * (1.f / 32.f));
    }
}

// ---------------- MFMA GEMM: C[512,4096] = A[512,2048]bf16 @ lw[4096,2048]fp32^T + lb
// B converted fp32->bf16 inline during LDS staging
__global__ __launch_bounds__(256) void lin_gemm_mfma(const __hip_bfloat16* __restrict__ A,
                                                     const float* __restrict__ Bw,
                                                     const float* __restrict__ bias,
                                                     float* __restrict__ C) {
    __shared__ uint4 A_s[64 * 8];
    __shared__ uint4 B_s[128 * 8];
    int t = threadIdx.x;
    int col0 = blockIdx.x * 128;
    int row0 = blockIdx.y * 64;
    int w = t >> 6, lane = t & 63;
    int m = lane & 15, quad = lane >> 4;

    f32x4 acc[8];
#pragma unroll
    for (int nt = 0; nt < 8; ++nt) acc[nt] = (f32x4){0.f, 0.f, 0.f, 0.f};

    for (int ki = 0; ki < 32; ++ki) {
        int k0 = ki * 64;
#pragma unroll
        for (int p = 0; p < 2; ++p) {
            int id = p * 256 + t;
            int r = id >> 3, u = id & 7;
            A_s[r * 8 + (u ^ (r & 7))] = *(const uint4*)(A + (row0 + r) * 2048 + k0 + u * 8);
        }
#pragma unroll
        for (int p = 0; p < 4; ++p) {
            int id = p * 256 + t;
            int r = id >> 3, u = id & 7;
            const float4* s4 = (const float4*)(Bw + (size_t)(col0 + r) * 2048 + k0 + u * 8);
            float4 f0 = s4[0], f1 = s4[1];
            union { uint4 q; __hip_bfloat16 h[8]; } o;
            o.h[0] = __float2bfloat16(f0.x); o.h[1] = __float2bfloat16(f0.y);
            o.h[2] = __float2bfloat16(f0.z); o.h[3] = __float2bfloat16(f0.w);
            o.h[4] = __float2bfloat16(f1.x); o.h[5] = __float2bfloat16(f1.y);
            o.h[6] = __float2bfloat16(f1.z); o.h[7] = __float2bfloat16(f1.w);
            B_s[r * 8 + (u ^ (r & 7))] = o.q;
        }
        __syncthreads();
#pragma unroll
        for (int c = 0; c < 2; ++c) {
            int ra = w * 16 + m;
            int ua = c * 4 + quad;
            U4 av; av.u = A_s[ra * 8 + (ua ^ (ra & 7))];
#pragma unroll
            for (int nt = 0; nt < 8; ++nt) {
                int rb = nt * 16 + m;
                U4 bv; bv.u = B_s[rb * 8 + (ua ^ (rb & 7))];
                acc[nt] = __builtin_amdgcn_mfma_f32_16x16x32_bf16(av.s8, bv.s8, acc[nt], 0, 0, 0);
            }
        }
        __syncthreads();
    }
#pragma unroll
    for (int nt = 0; nt < 8; ++nt) {
        int col = col0 + nt * 16 + m;
        float bv = bias[col];
#pragma unroll
        for (int reg = 0; reg < 4; ++reg) {
            int row = row0 + w * 16 + quad * 4 + reg;
            C[row * 4096 + col] = acc[nt][reg] + bv;
        }
    }
}

// ---------------- fused double {layernorm + mamba}: [B,64,64] -> [B,64,64]
// LDS diet: X (input->xln->z->out1), XI (xi->u->gated y, all in place), W12 (dt|B|C). 38 KB -> 3 blocks/CU.
struct MambaP {
    const float *lng, *lnb, *inw, *cvw, *cvb, *xpw, *dtw, *dtb, *al, *dp, *ow;
};

__global__ __launch_bounds__(256, 3) void mamba2_kernel(const float* __restrict__ lin,
                                                        MambaP p1, MambaP p2,
                                                        float* __restrict__ out) {
    __shared__ float X[64][68];     // input -> xln; z parked here after in-proj; blk0 output
    __shared__ float XI[64][68];    // xi -> u -> gated y (in place)
    __shared__ float W12[64][13];   // [dt0..3 | B0..3 | C0..3]
    int b = blockIdx.x, t = threadIdx.x;

    {
        const float4* lin4 = (const float4*)(lin + b * 4096);
        for (int i = t; i < 1024; i += 256) {
            float4 v = lin4[i];
            *(float4*)(&X[i >> 4][(i & 15) * 4]) = v;
        }
    }
    __syncthreads();

    for (int blk = 0; blk < 2; ++blk) {
        MambaP P = blk ? p2 : p1;

        // ---- LayerNorm (in place), thread (l = t>>2, q = t&3), width-4 shuffle reduce
        {
            int l = t >> 2, q = t & 3;
            float4 xv[4];
            const float4* xr = (const float4*)(&X[l][q * 16]);
#pragma unroll
            for (int j = 0; j < 4; ++j) xv[j] = xr[j];
            float s = 0.f;
#pragma unroll
            for (int j = 0; j < 4; ++j) s += (xv[j].x + xv[j].y) + (xv[j].z + xv[j].w);
            s += __shfl_xor(s, 1, 4);
            s += __shfl_xor(s, 2, 4);
            float m = s * (1.f / 64.f);
            float v = 0.f;
#pragma unroll
            for (int j = 0; j < 4; ++j) {
                float dx;
                dx = xv[j].x - m; v = fmaf(dx, dx, v);
                dx = xv[j].y - m; v = fmaf(dx, dx, v);
                dx = xv[j].z - m; v = fmaf(dx, dx, v);
                dx = xv[j].w - m; v = fmaf(dx, dx, v);
            }
            v += __shfl_xor(v, 1, 4);
            v += __shfl_xor(v, 2, 4);
            float rstd = rsqrtf(v * (1.f / 64.f) + 1e-5f);
            const float4* g4 = (const float4*)(P.lng + q * 16);
            const float4* bb4 = (const float4*)(P.lnb + q * 16);
            float4* xw = (float4*)(&X[l][q * 16]);
#pragma unroll
            for (int j = 0; j < 4; ++j) {
                float4 g = g4[j], bb = bb4[j], o;
                o.x = (xv[j].x - m) * rstd * g.x + bb.x;
                o.y = (xv[j].y - m) * rstd * g.y + bb.y;
                o.z = (xv[j].z - m) * rstd * g.z + bb.z;
                o.w = (xv[j].w - m) * rstd * g.w + bb.w;
                xw[j] = o;
            }
        }
        __syncthreads();

        // ---- in-projection: e<64 -> XI; e>=64 -> z kept in regs (X still being read)
        float zreg[32];
        {
            int e = t & 127, half = t >> 7;
            const float4* w4p = (const float4*)(P.inw + e * 64);
            float4 W[16];
#pragma unroll
            for (int k4 = 0; k4 < 16; ++k4) W[k4] = w4p[k4];
            bool isz = (e >= 64);
#pragma unroll 2
            for (int i = 0; i < 32; ++i) {
                int l = half * 32 + i;
                const float4* xr = (const float4*)(&X[l][0]);
                float a0 = 0.f, a1 = 0.f, a2 = 0.f, a3 = 0.f;
#pragma unroll
                for (int k4 = 0; k4 < 16; ++k4) {
                    float4 xv = xr[k4];
                    a0 = fmaf(xv.x, W[k4].x, a0);
                    a1 = fmaf(xv.y, W[k4].y, a1);
                    a2 = fmaf(xv.z, W[k4].z, a2);
                    a3 = fmaf(xv.w, W[k4].w, a3);
                }
                float acc = (a0 + a1) + (a2 + a3);
                if (isz) zreg[i] = acc; else XI[l][e] = acc;
            }
        }
        __syncthreads();

        // ---- depthwise conv(k=2)+silu on XI (in place) + park z into now-dead X region
        {
            int d = t & 63, lg = t >> 6;
            int l0 = lg * 16;
            float cur[16];
            float prev = (l0 == 0) ? 0.f : XI[l0 - 1][d];
#pragma unroll
            for (int j = 0; j < 16; ++j) cur[j] = XI[l0 + j][d];
            {   // z spill: X is dead (LN output fully consumed by in-proj)
                int ez = t & 127, hz = t >> 7;
                if (ez >= 64) {
                    int dz = ez - 64;
#pragma unroll 4
                    for (int i = 0; i < 32; ++i) X[hz * 32 + i][dz] = zreg[i];
                }
            }
            __syncthreads();
            float w0 = P.cvw[d * 2], w1 = P.cvw[d * 2 + 1], cb = P.cvb[d];
#pragma unroll
            for (int j = 0; j < 16; ++j) {
                float xp = (j == 0) ? prev : cur[j - 1];
                float v = fmaf(w0, xp, fmaf(w1, cur[j], cb));
                XI[l0 + j][d] = v / (1.f + __expf(-v));
            }
        }
        __syncthreads();

        // ---- x_dbl = u @ xpw^T -> W12[l][0..11]
        {
            int l = t & 63, jg = t >> 6;
            float4 xrow[16];
            const float4* xr = (const float4*)(&XI[l][0]);
#pragma unroll
            for (int k4 = 0; k4 < 16; ++k4) xrow[k4] = xr[k4];
#pragma unroll
            for (int jj = 0; jj < 3; ++jj) {
                int j = jg * 3 + jj;
                const float4* wr = (const float4*)(P.xpw + j * 64);
                float a0 = 0.f, a1 = 0.f, a2 = 0.f, a3 = 0.f;
#pragma unroll
                for (int k4 = 0; k4 < 16; ++k4) {
                    float4 wv = wr[k4];
                    a0 = fmaf(xrow[k4].x, wv.x, a0);
                    a1 = fmaf(xrow[k4].y, wv.y, a1);
                    a2 = fmaf(xrow[k4].z, wv.z, a2);
                    a3 = fmaf(xrow[k4].w, wv.w, a3);
                }
                W12[l][j] = (a0 + a1) + (a2 + a3);
            }
        }
        __syncthreads();

        // ---- selective scan: thread (d = t>>2, n = t&3); softplus inline; gated y in place into XI
        {
            int d = t >> 2, n = t & 3;
            float Aval = -__expf(P.al[d * 4 + n]);
            float dpv = P.dp[d];
            float4 dw = *(const float4*)(P.dtw + d * 4);
            float db = P.dtb[d];
            float h = 0.f;
            for (int l = 0; l < 64; ++l) {
                const float* wr = &W12[l][0];
                float xdt = fmaf(dw.x, wr[0], fmaf(dw.y, wr[1], fmaf(dw.z, wr[2], fmaf(dw.w, wr[3], db))));
                float dtv = fmaxf(xdt, 0.f) + __logf(1.f + __expf(-fabsf(xdt)));
                float dA = __expf(dtv * Aval);
                float uv = XI[l][d];
                h = fmaf(dA, h, dtv * wr[4 + n] * uv);
                float part = h * wr[8 + n];
                part += __shfl_xor(part, 1, 4);
                part += __shfl_xor(part, 2, 4);
                if (n == 0) {
                    float zv = X[l][d];                 // z parked in X
                    float yv = part + dpv * uv;
                    XI[l][d] = yv * (zv / (1.f + __expf(-zv)));
                }
            }
        }
        __syncthreads();

        // ---- out-projection: reads gated y from XI (broadcast rows); blk0 result -> X
        {
            int eo = t & 63, lg = t >> 6;
            const float4* wp = (const float4*)(P.ow + eo * 64);
            float4 W[16];
#pragma unroll
            for (int k4 = 0; k4 < 16; ++k4) W[k4] = wp[k4];
#pragma unroll 2
            for (int ii = 0; ii < 16; ++ii) {
                int l = lg * 16 + ii;
                const float4* yr = (const float4*)(&XI[l][0]);
                float a0 = 0.f, a1 = 0.f, a2 = 0.f, a3 = 0.f;
#pragma unroll
                for (int k4 = 0; k4 < 16; ++k4) {
                    float4 yv = yr[k4];
                    a0 = fmaf(yv.x, W[k4].x, a0);
                    a1 = fmaf(yv.y, W[k4].y, a1);
                    a2 = fmaf(yv.z, W[k4].z, a2);
                    a3 = fmaf(yv.w, W[k4].w, a3);
                }
                float acc = (a0 + a1) + (a2 + a3);
                if (blk == 0) X[l][eo] = acc;
                else out[b * 4096 + l * 64 + eo] = acc;
            }
        }
        __syncthreads();
    }
}

extern "C" void kernel_launch(void* const* d_in, const int* in_sizes, int n_in,
                              void* d_out, int out_size, void* d_ws, size_t ws_size,
                              hipStream_t stream) {
    const float* x   = (const float*)d_in[0];
    const float* c1w = (const float*)d_in[1];
    const float* c1b = (const float*)d_in[2];
    const float* c2w = (const float*)d_in[3];
    const float* c2b = (const float*)d_in[4];
    const float* c3w = (const float*)d_in[5];
    const float* c3b = (const float*)d_in[6];
    const float* lw  = (const float*)d_in[7];
    const float* lb  = (const float*)d_in[8];

    MambaP p1, p2;
    p1.lng = (const float*)d_in[9];  p1.lnb = (const float*)d_in[10];
    p1.inw = (const float*)d_in[11]; p1.cvw = (const float*)d_in[12];
    p1.cvb = (const float*)d_in[13]; p1.xpw = (const float*)d_in[14];
    p1.dtw = (const float*)d_in[15]; p1.dtb = (const float*)d_in[16];
    p1.al  = (const float*)d_in[17]; p1.dp  = (const float*)d_in[18];
    p1.ow  = (const float*)d_in[19];
    p2.lng = (const float*)d_in[20]; p2.lnb = (const float*)d_in[21];
    p2.inw = (const float*)d_in[22]; p2.cvw = (const float*)d_in[23];
    p2.cvb = (const float*)d_in[24]; p2.xpw = (const float*)d_in[25];
    p2.dtw = (const float*)d_in[26]; p2.dtb = (const float*)d_in[27];
    p2.al  = (const float*)d_in[28]; p2.dp  = (const float*)d_in[29];
    p2.ow  = (const float*)d_in[30];

    const size_t MB = 1024 * 1024;
    char* base = (char*)d_ws;
    __hip_bfloat16* w2b = (__hip_bfloat16*)base;                 // 6 KB
    __hip_bfloat16* w3b = (__hip_bfloat16*)(base + 32 * 1024);   // 20 KB
    __hip_bfloat16* h3b = (__hip_bfloat16*)(base + 1 * MB);      // 2 MB
    float* lin          = (float*)(base + 4 * MB);               // 8 MB
    float* outp = (float*)d_out;

    prep_w<<<dim3(52), dim3(256), 0, stream>>>(c2w, w2b, c3w, w3b);
    conv_trunk<<<dim3(NB), dim3(256), 0, stream>>>(x, c1w, c1b, w2b, c2b, w3b, c3b, h3b);
    lin_gemm_mfma<<<dim3(32, 8), dim3(256), 0, stream>>>(h3b, lw, lb, lin);
    mamba2_kernel<<<dim3(NB), dim3(256), 0, stream>>>(lin, p1, p2, outp);
}

// Round 7
// 287.191 us; speedup vs baseline: 7.2001x; 1.2239x over previous
//
#include <hip/hip_runtime.h>
#include <hip/hip_bf16.h>
#include <math.h>

#define NB 512

typedef __attribute__((ext_vector_type(8))) short short8;
typedef __attribute__((ext_vector_type(4))) float f32x4;
union U4 { uint4 u; short8 s8; };
union BF { __hip_bfloat16 h; ushort us; };

__device__ __forceinline__ int swz(int u) { return u ^ ((u >> 3) & 7); }
__device__ __forceinline__ int idx8(int l, int u) { return l * 8 + (u ^ (l & 7)); }

// ---------------- prep: lw->bf16 + conv weight reorg + mamba weight bf16
__global__ __launch_bounds__(256) void prep_all(const float4* __restrict__ lw4,
                                                ushort4* __restrict__ lwb4,
                                                const float* __restrict__ w2,
                                                __hip_bfloat16* __restrict__ w2b,
                                                const float* __restrict__ w3,
                                                __hip_bfloat16* __restrict__ w3b,
                                                const float* __restrict__ in1w,
                                                const float* __restrict__ in2w,
                                                __hip_bfloat16* __restrict__ winb,
                                                const float* __restrict__ ow1,
                                                const float* __restrict__ ow2,
                                                __hip_bfloat16* __restrict__ owb) {
    int blk = blockIdx.x, t = threadIdx.x;
    if (blk < 8192) {
        int i = blk * 256 + t;
        float4 v = lw4[i];
        union { ushort4 u; __hip_bfloat16 h[4]; } o;
        o.h[0] = __float2bfloat16(v.x);
        o.h[1] = __float2bfloat16(v.y);
        o.h[2] = __float2bfloat16(v.z);
        o.h[3] = __float2bfloat16(v.w);
        lwb4[i] = o.u;
    } else if (blk == 8192) {
        for (int i = t; i < 3072; i += 256) {
            int c2 = i / 96, rest = i - c2 * 96;
            int tp = rest >> 5, r2 = rest & 31;
            int tl = r2 >> 4, c1 = r2 & 15;
            int tap = tp * 2 + tl;
            float v = (tap < 5) ? w2[c2 * 80 + c1 * 5 + tap] : 0.f;
            w2b[i] = __float2bfloat16(v);
        }
        for (int i = t; i < 10240; i += 256) {
            int c3 = i / 160, rest = i - c3 * 160;
            int kk = rest >> 5, c1 = rest & 31;
            w3b[i] = __float2bfloat16(w3[c3 * 160 + c1 * 5 + kk]);
        }
    } else {
        for (int i = t; i < 16384; i += 256)
            winb[i] = __float2bfloat16((i < 8192 ? in1w : in2w)[i & 8191]);
        for (int i = t; i < 8192; i += 256)
            owb[i] = __float2bfloat16((i < 4096 ? ow1 : ow2)[i & 4095]);
    }
}

// ---------------- fused conv trunk, 2 blocks per batch (halo recompute), ~70 KB LDS
__global__ __launch_bounds__(256) void conv_trunk(const float* __restrict__ x,
                                                  const float* __restrict__ c1w,
                                                  const float* __restrict__ c1b,
                                                  const __hip_bfloat16* __restrict__ w2b,
                                                  const float* __restrict__ c2b,
                                                  const __hip_bfloat16* __restrict__ w3b,
                                                  const float* __restrict__ c3b,
                                                  __hip_bfloat16* __restrict__ h3b) {
    __shared__ uint4 H1u[2200];   // h1 rows r: pos p0+r, 2 units/row, swizzled (rows 0..1095)
    __shared__ uint4 H2u[2176];   // h2 pooled rows rr: global J0+rr, 4 units/row (rows 0..543)
    float* xs = (float*)H2u;      // alias: raw input staged here during phase 1 only
    int t = threadIdx.x, h = blockIdx.x, b = blockIdx.y;
    int lane = t & 63, w = t >> 6, m = lane & 15, quad = lane >> 4;
    int p0 = 1024 * h - 6;

    // ---- stage x (covers h1 rows [0,1096) -> x [2p0-2, 2p0+2196))
    const float* xb = x + b * 4096;
    int gbase = 2 * p0 - 2;
    for (int i = t; i < 2200; i += 256) {
        int gx = gbase + i;
        xs[i] = (gx >= 0 && gx < 4096) ? xb[gx] : 0.f;
    }
    // hoist conv2 B-fragments + conv1 weights
    U4 Bf2[3][2];
    {
        const uint4* wsrc = (const uint4*)w2b;
#pragma unroll
        for (int ct = 0; ct < 2; ++ct)
#pragma unroll
            for (int tp = 0; tp < 3; ++tp)
                Bf2[tp][ct].u = wsrc[(ct * 16 + m) * 12 + tp * 4 + quad];
    }
    float bv2[2];
#pragma unroll
    for (int ct = 0; ct < 2; ++ct) bv2[ct] = c2b[ct * 16 + m];
    float wv[80], bv1[16];
#pragma unroll
    for (int i = 0; i < 80; ++i) wv[i] = c1w[i];
#pragma unroll
    for (int i = 0; i < 16; ++i) bv1[i] = c1b[i];
    __syncthreads();

    // ---- phase 1: conv1(k5)+maxpool2+relu -> H1 rows [0,1096)
    for (int r = t; r < 1096; r += 256) {
        int p = p0 + r;
        union { uint4 q[2]; __hip_bfloat16 hh[16]; } o;
        if (p >= 0 && p < 2048) {
            const float* s = xs + 2 * r;
            float s0 = s[0], s1 = s[1], s2 = s[2], s3 = s[3], s4 = s[4], s5 = s[5];
#pragma unroll
            for (int c = 0; c < 16; ++c) {
                const float* wr = wv + c * 5;
                float v0 = fmaf(wr[0], s0, fmaf(wr[1], s1, fmaf(wr[2], s2, fmaf(wr[3], s3, fmaf(wr[4], s4, bv1[c])))));
                float v1 = fmaf(wr[0], s1, fmaf(wr[1], s2, fmaf(wr[2], s3, fmaf(wr[3], s4, fmaf(wr[4], s5, bv1[c])))));
                o.hh[c] = __float2bfloat16(fmaxf(fmaxf(v0, v1), 0.f));
            }
        } else {
            o.q[0] = (uint4){0, 0, 0, 0};
            o.q[1] = (uint4){0, 0, 0, 0};
        }
        H1u[swz(2 * r)] = o.q[0];
        H1u[swz(2 * r + 1)] = o.q[1];
    }
    __syncthreads();

    // ---- phase 2: conv2(k5)+maxpool2+relu MFMA -> H2 rows (pooled local rr = 8g+2*quad..)
    __hip_bfloat16* H2h = (__hip_bfloat16*)H2u;
    for (int g = w; g < 68; g += 4) {
        f32x4 acc[2];
#pragma unroll
        for (int ct = 0; ct < 2; ++ct) acc[ct] = (f32x4){bv2[ct], bv2[ct], bv2[ct], bv2[ct]};
#pragma unroll
        for (int tp = 0; tp < 3; ++tp) {
            int u = 2 * (g * 16 + m + 2 * tp) + quad;
            U4 av; av.u = H1u[swz(u)];
            acc[0] = __builtin_amdgcn_mfma_f32_16x16x32_bf16(av.s8, Bf2[tp][0].s8, acc[0], 0, 0, 0);
            acc[1] = __builtin_amdgcn_mfma_f32_16x16x32_bf16(av.s8, Bf2[tp][1].s8, acc[1], 0, 0, 0);
        }
        int pp = g * 8 + quad * 2;
#pragma unroll
        for (int ct = 0; ct < 2; ++ct) {
            float o0 = fmaxf(fmaxf(acc[ct][0], acc[ct][1]), 0.f);
            float o1 = fmaxf(fmaxf(acc[ct][2], acc[ct][3]), 0.f);
            int ch = ct * 16 + m;
            int u0 = pp * 4 + (ch >> 3);
            H2h[swz(u0) * 8 + (ch & 7)] = __float2bfloat16(o0);
            H2h[swz(u0 + 4) * 8 + (ch & 7)] = __float2bfloat16(o1);
        }
    }
    __syncthreads();
    // zero the out-of-range pooled rows (reference zero-pads h2 for conv3)
    if (t < 8) {
        int row = (h == 0) ? (t >> 2) : (514 + (t >> 2));
        H2u[swz(row * 4 + (t & 3))] = (uint4){0, 0, 0, 0};
    }
    __syncthreads();

    // ---- phase 3: conv3(k5)+relu+avgpool(32) MFMA -> h3b (16 windows per block)
    U4 Bf3[5][4];
    {
        const uint4* wsrc = (const uint4*)w3b;
#pragma unroll
        for (int ct = 0; ct < 4; ++ct)
#pragma unroll
            for (int kk = 0; kk < 5; ++kk)
                Bf3[kk][ct].u = wsrc[(ct * 16 + m) * 20 + kk * 4 + quad];
    }
    float bv3[4];
#pragma unroll
    for (int ct = 0; ct < 4; ++ct) bv3[ct] = c3b[ct * 16 + m];

    for (int ii = 0; ii < 4; ++ii) {
        int wl = w * 4 + ii;
        float sum[4] = {0.f, 0.f, 0.f, 0.f};
#pragma unroll
        for (int half = 0; half < 2; ++half) {
            int gp = wl * 2 + half;
            f32x4 acc[4];
#pragma unroll
            for (int ct = 0; ct < 4; ++ct) acc[ct] = (f32x4){bv3[ct], bv3[ct], bv3[ct], bv3[ct]};
#pragma unroll
            for (int kk = 0; kk < 5; ++kk) {
                int u = 4 * (gp * 16 + m + kk) + quad;
                U4 av; av.u = H2u[swz(u)];
#pragma unroll
                for (int ct = 0; ct < 4; ++ct)
                    acc[ct] = __builtin_amdgcn_mfma_f32_16x16x32_bf16(av.s8, Bf3[kk][ct].s8, acc[ct], 0, 0, 0);
            }
#pragma unroll
            for (int ct = 0; ct < 4; ++ct) {
                sum[ct] += fmaxf(acc[ct][0], 0.f) + fmaxf(acc[ct][1], 0.f)
                         + fmaxf(acc[ct][2], 0.f) + fmaxf(acc[ct][3], 0.f);
            }
        }
#pragma unroll
        for (int ct = 0; ct < 4; ++ct) {
            float s = sum[ct];
            s += __shfl_xor(s, 16, 64);
            s += __shfl_xor(s, 32, 64);
            sum[ct] = s;
        }
        float sv = (quad == 0) ? sum[0] : (quad == 1) ? sum[1] : (quad == 2) ? sum[2] : sum[3];
        int win = h * 16 + wl;
        h3b[b * 2048 + (quad * 16 + m) * 32 + win] = __float2bfloat16(sv * (1.f / 32.f));
    }
}

// ---------------- MFMA GEMM: C[512,4096] = A[512,2048]bf16 @ B[4096,2048]bf16^T + lb
// 64x64 tile, grid (64,8)=512 blocks (2/CU)
__global__ __launch_bounds__(256) void lin_gemm_mfma(const __hip_bfloat16* __restrict__ A,
                                                     const __hip_bfloat16* __restrict__ B,
                                                     const float* __restrict__ bias,
                                                     float* __restrict__ C) {
    __shared__ uint4 A_s[512];
    __shared__ uint4 B_s[512];
    int t = threadIdx.x;
    int col0 = blockIdx.x * 64;
    int row0 = blockIdx.y * 64;
    int w = t >> 6, lane = t & 63;
    int m = lane & 15, quad = lane >> 4;
    int lh = w >> 1, eh = w & 1;

    f32x4 acc[2][2];
#pragma unroll
    for (int li = 0; li < 2; ++li)
#pragma unroll
        for (int ei = 0; ei < 2; ++ei) acc[li][ei] = (f32x4){0.f, 0.f, 0.f, 0.f};

    for (int ki = 0; ki < 32; ++ki) {
        int k0 = ki * 64;
#pragma unroll
        for (int p = 0; p < 2; ++p) {
            int id = p * 256 + t;
            int r = id >> 3, u = id & 7;
            A_s[r * 8 + (u ^ (r & 7))] = *(const uint4*)(A + (row0 + r) * 2048 + k0 + u * 8);
            B_s[r * 8 + (u ^ (r & 7))] = *(const uint4*)(B + (size_t)(col0 + r) * 2048 + k0 + u * 8);
        }
        __syncthreads();
#pragma unroll
        for (int c = 0; c < 2; ++c) {
            int uu = c * 4 + quad;
            U4 av[2], bv[2];
#pragma unroll
            for (int li = 0; li < 2; ++li) {
                int ra = (lh * 2 + li) * 16 + m;
                av[li].u = A_s[ra * 8 + (uu ^ (ra & 7))];
            }
#pragma unroll
            for (int ei = 0; ei < 2; ++ei) {
                int rb = (eh * 2 + ei) * 16 + m;
                bv[ei].u = B_s[rb * 8 + (uu ^ (rb & 7))];
            }
#pragma unroll
            for (int li = 0; li < 2; ++li)
#pragma unroll
                for (int ei = 0; ei < 2; ++ei)
                    acc[li][ei] = __builtin_amdgcn_mfma_f32_16x16x32_bf16(av[li].s8, bv[ei].s8, acc[li][ei], 0, 0, 0);
        }
        __syncthreads();
    }
#pragma unroll
    for (int li = 0; li < 2; ++li)
#pragma unroll
        for (int ei = 0; ei < 2; ++ei) {
            int col = col0 + (eh * 2 + ei) * 16 + m;
            float bvv = bias[col];
#pragma unroll
            for (int reg = 0; reg < 4; ++reg) {
                int row = row0 + (lh * 2 + li) * 16 + quad * 4 + reg;
                C[row * 4096 + col] = acc[li][ei][reg] + bvv;
            }
        }
}

// ---------------- fused double {layernorm + mamba}, MFMA in/out-proj
struct MambaP {
    const float *lng, *lnb, *cvw, *cvb, *xpw, *dtw, *dtb, *al, *dp;
};

__global__ __launch_bounds__(256) void mamba2_kernel(const float* __restrict__ lin,
                                                     const __hip_bfloat16* __restrict__ winb,
                                                     const __hip_bfloat16* __restrict__ owb,
                                                     MambaP p1, MambaP p2,
                                                     float* __restrict__ out) {
    __shared__ float X[64][68];     // input -> (z after in-proj) -> blk0 output
    __shared__ float XI[64][68];    // xi -> u (in place)
    __shared__ float DTS[64][68];   // softplus(dt) transposed [d][l]
    __shared__ float W12[64][14];   // dt0..3 | (B,C) interleaved pairs at 4+2n
    __shared__ uint4 XBu[512];      // bf16 A-operand: LN-out, then gated y
    int b = blockIdx.x, t = threadIdx.x;
    int lane = t & 63, w = t >> 6, m = lane & 15, quad = lane >> 4;
    int l0 = w * 16;

    {
        const float4* lin4 = (const float4*)(lin + b * 4096);
        for (int i = t; i < 1024; i += 256) {
            float4 v = lin4[i];
            *(float4*)(&X[i >> 4][(i & 15) * 4]) = v;
        }
    }
    __syncthreads();

    for (int blk = 0; blk < 2; ++blk) {
        MambaP P = blk ? p2 : p1;

        // ---- LayerNorm: thread (l = t>>2, q = t&3); output ONLY to bf16 XBu
        {
            int l = t >> 2, q = t & 3;
            float4 xv[4];
            const float4* xr = (const float4*)(&X[l][q * 16]);
#pragma unroll
            for (int j = 0; j < 4; ++j) xv[j] = xr[j];
            float s = 0.f;
#pragma unroll
            for (int j = 0; j < 4; ++j) s += (xv[j].x + xv[j].y) + (xv[j].z + xv[j].w);
            s += __shfl_xor(s, 1, 4);
            s += __shfl_xor(s, 2, 4);
            float mm = s * (1.f / 64.f);
            float v = 0.f;
#pragma unroll
            for (int j = 0; j < 4; ++j) {
                float dx;
                dx = xv[j].x - mm; v = fmaf(dx, dx, v);
                dx = xv[j].y - mm; v = fmaf(dx, dx, v);
                dx = xv[j].z - mm; v = fmaf(dx, dx, v);
                dx = xv[j].w - mm; v = fmaf(dx, dx, v);
            }
            v += __shfl_xor(v, 1, 4);
            v += __shfl_xor(v, 2, 4);
            float rstd = rsqrtf(v * (1.f / 64.f) + 1e-5f);
            const float4* g4 = (const float4*)(P.lng + q * 16);
            const float4* bb4 = (const float4*)(P.lnb + q * 16);
            union { uint4 qq[2]; __hip_bfloat16 hh[16]; } o;
#pragma unroll
            for (int j = 0; j < 4; ++j) {
                float4 g = g4[j], bb = bb4[j];
                o.hh[j * 4 + 0] = __float2bfloat16((xv[j].x - mm) * rstd * g.x + bb.x);
                o.hh[j * 4 + 1] = __float2bfloat16((xv[j].y - mm) * rstd * g.y + bb.y);
                o.hh[j * 4 + 2] = __float2bfloat16((xv[j].z - mm) * rstd * g.z + bb.z);
                o.hh[j * 4 + 3] = __float2bfloat16((xv[j].w - mm) * rstd * g.w + bb.w);
            }
            XBu[idx8(l, q * 2)] = o.qq[0];
            XBu[idx8(l, q * 2 + 1)] = o.qq[1];
        }
        __syncthreads();

        // ---- in-projection MFMA: xz[l][e] ; e<64 -> XI fp32, e>=64 -> z into X
        {
            const uint4* wp = (const uint4*)winb + blk * 1024;
            U4 Bf[8][2];
#pragma unroll
            for (int nt = 0; nt < 8; ++nt)
#pragma unroll
                for (int c = 0; c < 2; ++c)
                    Bf[nt][c].u = wp[(nt * 16 + m) * 8 + c * 4 + quad];
            f32x4 acc[8];
#pragma unroll
            for (int nt = 0; nt < 8; ++nt) acc[nt] = (f32x4){0.f, 0.f, 0.f, 0.f};
#pragma unroll
            for (int c = 0; c < 2; ++c) {
                U4 av; av.u = XBu[idx8(l0 + m, c * 4 + quad)];
#pragma unroll
                for (int nt = 0; nt < 8; ++nt)
                    acc[nt] = __builtin_amdgcn_mfma_f32_16x16x32_bf16(av.s8, Bf[nt][c].s8, acc[nt], 0, 0, 0);
            }
#pragma unroll
            for (int nt = 0; nt < 4; ++nt)
#pragma unroll
                for (int reg = 0; reg < 4; ++reg)
                    XI[l0 + quad * 4 + reg][nt * 16 + m] = acc[nt][reg];
#pragma unroll
            for (int nt = 4; nt < 8; ++nt)
#pragma unroll
                for (int reg = 0; reg < 4; ++reg)
                    X[l0 + quad * 4 + reg][(nt - 4) * 16 + m] = acc[nt][reg];
        }
        __syncthreads();

        // ---- causal depthwise conv(k=2)+silu, in place on XI
        {
            int d = t & 63, lg = t >> 6;
            int lc = lg * 16;
            float cur[16];
            float prev = (lc == 0) ? 0.f : XI[lc - 1][d];
#pragma unroll
            for (int j = 0; j < 16; ++j) cur[j] = XI[lc + j][d];
            __syncthreads();
            float w0 = P.cvw[d * 2], w1 = P.cvw[d * 2 + 1], cb = P.cvb[d];
#pragma unroll
            for (int j = 0; j < 16; ++j) {
                float xp = (j == 0) ? prev : cur[j - 1];
                float v = fmaf(w0, xp, fmaf(w1, cur[j], cb));
                XI[lc + j][d] = v / (1.f + __expf(-v));
            }
        }
        __syncthreads();

        // ---- x_dbl = u @ xpw^T -> W12 (dt 0..3; B,C interleaved at 4+2n / 5+2n)
        {
            int l = t & 63, jg = t >> 6;
            float4 xrow[16];
            const float4* xr = (const float4*)(&XI[l][0]);
#pragma unroll
            for (int k4 = 0; k4 < 16; ++k4) xrow[k4] = xr[k4];
#pragma unroll
            for (int jj = 0; jj < 3; ++jj) {
                int j = jg * 3 + jj;
                const float4* wr = (const float4*)(P.xpw + j * 64);
                float a0 = 0.f, a1 = 0.f, a2 = 0.f, a3 = 0.f;
#pragma unroll
                for (int k4 = 0; k4 < 16; ++k4) {
                    float4 wvv = wr[k4];
                    a0 = fmaf(xrow[k4].x, wvv.x, a0);
                    a1 = fmaf(xrow[k4].y, wvv.y, a1);
                    a2 = fmaf(xrow[k4].z, wvv.z, a2);
                    a3 = fmaf(xrow[k4].w, wvv.w, a3);
                }
                float accv = (a0 + a1) + (a2 + a3);
                int slot = (j < 4) ? j : ((j < 8) ? (4 + (j - 4) * 2) : (5 + (j - 8) * 2));
                W12[l][slot] = accv;
            }
        }
        __syncthreads();

        // ---- softplus(dt) precompute, transposed
        {
            int l = t & 63, dg = t >> 6;
            float d0 = W12[l][0], d1 = W12[l][1], d2 = W12[l][2], d3 = W12[l][3];
#pragma unroll 4
            for (int jj = 0; jj < 16; ++jj) {
                int d = dg * 16 + jj;
                const float4 wvv = *(const float4*)(P.dtw + d * 4);
                float xdt = fmaf(wvv.x, d0, fmaf(wvv.y, d1, fmaf(wvv.z, d2, fmaf(wvv.w, d3, P.dtb[d]))));
                DTS[d][l] = fmaxf(xdt, 0.f) + __logf(1.f + __expf(-fabsf(xdt)));
            }
        }
        __syncthreads();

        // ---- selective scan: thread (d = t>>2, n = t&3); gated y -> bf16 XBu (as YB)
        {
            int d = t >> 2, n = t & 3;
            float Aval = -__expf(P.al[d * 4 + n]);
            float dpv = P.dp[d];
            const float* dtrow = &DTS[d][0];
            ushort* YBh = (ushort*)XBu;
            int ybase = 0;  // recomputed per l
            float h = 0.f;
            for (int l = 0; l < 64; ++l) {
                float dtv = dtrow[l];
                float dA = __expf(dtv * Aval);
                float uv = XI[l][d];
                float2 bc = *(const float2*)(&W12[l][4 + n * 2]);
                h = fmaf(dA, h, dtv * bc.x * uv);
                float part = h * bc.y;
                part += __shfl_xor(part, 1, 4);
                part += __shfl_xor(part, 2, 4);
                if (n == 0) {
                    float zv = X[l][d];
                    float yv = part + dpv * uv;
                    float gy = yv * (zv / (1.f + __expf(-zv)));
                    BF cv; cv.h = __float2bfloat16(gy);
                    YBh[idx8(l, d >> 3) * 8 + (d & 7)] = cv.us;
                }
                (void)ybase;
            }
        }
        __syncthreads();

        // ---- out-projection MFMA: reads YB (=XBu); blk0 -> X, blk1 -> global
        {
            const uint4* wp = (const uint4*)owb + blk * 512;
            U4 Bf[4][2];
#pragma unroll
            for (int nt = 0; nt < 4; ++nt)
#pragma unroll
                for (int c = 0; c < 2; ++c)
                    Bf[nt][c].u = wp[(nt * 16 + m) * 8 + c * 4 + quad];
            f32x4 acc[4];
#pragma unroll
            for (int nt = 0; nt < 4; ++nt) acc[nt] = (f32x4){0.f, 0.f, 0.f, 0.f};
#pragma unroll
            for (int c = 0; c < 2; ++c) {
                U4 av; av.u = XBu[idx8(l0 + m, c * 4 + quad)];
#pragma unroll
                for (int nt = 0; nt < 4; ++nt)
                    acc[nt] = __builtin_amdgcn_mfma_f32_16x16x32_bf16(av.s8, Bf[nt][c].s8, acc[nt], 0, 0, 0);
            }
            if (blk == 0) {
#pragma unroll
                for (int nt = 0; nt < 4; ++nt)
#pragma unroll
                    for (int reg = 0; reg < 4; ++reg)
                        X[l0 + quad * 4 + reg][nt * 16 + m] = acc[nt][reg];
            } else {
                float* ob = out + b * 4096;
#pragma unroll
                for (int nt = 0; nt < 4; ++nt)
#pragma unroll
                    for (int reg = 0; reg < 4; ++reg)
                        ob[(l0 + quad * 4 + reg) * 64 + nt * 16 + m] = acc[nt][reg];
            }
        }
        __syncthreads();
    }
}

extern "C" void kernel_launch(void* const* d_in, const int* in_sizes, int n_in,
                              void* d_out, int out_size, void* d_ws, size_t ws_size,
                              hipStream_t stream) {
    const float* x   = (const float*)d_in[0];
    const float* c1w = (const float*)d_in[1];
    const float* c1b = (const float*)d_in[2];
    const float* c2w = (const float*)d_in[3];
    const float* c2b = (const float*)d_in[4];
    const float* c3w = (const float*)d_in[5];
    const float* c3b = (const float*)d_in[6];
    const float* lw  = (const float*)d_in[7];
    const float* lb  = (const float*)d_in[8];

    MambaP p1, p2;
    p1.lng = (const float*)d_in[9];  p1.lnb = (const float*)d_in[10];
    p1.cvw = (const float*)d_in[12]; p1.cvb = (const float*)d_in[13];
    p1.xpw = (const float*)d_in[14]; p1.dtw = (const float*)d_in[15];
    p1.dtb = (const float*)d_in[16]; p1.al  = (const float*)d_in[17];
    p1.dp  = (const float*)d_in[18];
    p2.lng = (const float*)d_in[20]; p2.lnb = (const float*)d_in[21];
    p2.cvw = (const float*)d_in[23]; p2.cvb = (const float*)d_in[24];
    p2.xpw = (const float*)d_in[25]; p2.dtw = (const float*)d_in[26];
    p2.dtb = (const float*)d_in[27]; p2.al  = (const float*)d_in[28];
    p2.dp  = (const float*)d_in[29];
    const float* in1w = (const float*)d_in[11];
    const float* in2w = (const float*)d_in[22];
    const float* ow1  = (const float*)d_in[19];
    const float* ow2  = (const float*)d_in[30];

    const size_t MB = 1024 * 1024;
    char* base = (char*)d_ws;
    __hip_bfloat16* lwb  = (__hip_bfloat16*)base;                   // 16 MB
    __hip_bfloat16* h3b  = (__hip_bfloat16*)(base + 16 * MB);       // 2 MB
    float* lin           = (float*)(base + 20 * MB);                // 8 MB
    __hip_bfloat16* w2b  = (__hip_bfloat16*)(base + 28 * MB);       // 6 KB
    __hip_bfloat16* w3b  = (__hip_bfloat16*)(base + 28 * MB + 64 * 1024);   // 20 KB
    __hip_bfloat16* winb = (__hip_bfloat16*)(base + 28 * MB + 256 * 1024);  // 32 KB
    __hip_bfloat16* owb  = (__hip_bfloat16*)(base + 28 * MB + 512 * 1024);  // 16 KB
    float* outp = (float*)d_out;

    prep_all<<<dim3(8194), dim3(256), 0, stream>>>((const float4*)lw, (ushort4*)lwb,
                                                   c2w, w2b, c3w, w3b,
                                                   in1w, in2w, winb, ow1, ow2, owb);
    conv_trunk<<<dim3(2, NB), dim3(256), 0, stream>>>(x, c1w, c1b, w2b, c2b, w3b, c3b, h3b);
    lin_gemm_mfma<<<dim3(64, 8), dim3(256), 0, stream>>>(h3b, lwb, lb, lin);
    mamba2_kernel<<<dim3(NB), dim3(256), 0, stream>>>(lin, winb, owb, p1, p2, outp);
}

// Round 8
// 266.995 us; speedup vs baseline: 7.7447x; 1.0756x over previous
//
#include <hip/hip_runtime.h>
#include <hip/hip_bf16.h>
#include <math.h>

#define NB 512

typedef __attribute__((ext_vector_type(8))) short short8;
typedef __attribute__((ext_vector_type(4))) float f32x4;
union U4 { uint4 u; short8 s8; };
union BF { __hip_bfloat16 h; ushort us; };

__device__ __forceinline__ int swz(int u) { return u ^ ((u >> 3) & 7); }
__device__ __forceinline__ int idx8(int l, int u) { return l * 8 + (u ^ (l & 7)); }

// ---------------- small prep: conv weight reorg + mamba weight bf16 (148 blocks)
__global__ __launch_bounds__(256) void prep_w(const float* __restrict__ w2,
                                              __hip_bfloat16* __restrict__ w2b,
                                              const float* __restrict__ w3,
                                              __hip_bfloat16* __restrict__ w3b,
                                              const float* __restrict__ in1w,
                                              const float* __restrict__ in2w,
                                              __hip_bfloat16* __restrict__ winb,
                                              const float* __restrict__ ow1,
                                              const float* __restrict__ ow2,
                                              __hip_bfloat16* __restrict__ owb) {
    int i = blockIdx.x * 256 + threadIdx.x;   // 148*256 = 37888
    if (i < 3072) {
        // w2b[c2][tp*32 + tl*16 + c1] = (tap=2tp+tl)<5 ? w2[c2*80 + c1*5 + tap] : 0
        int c2 = i / 96, rest = i - c2 * 96;
        int tp = rest >> 5, r2 = rest & 31;
        int tl = r2 >> 4, c1 = r2 & 15;
        int tap = tp * 2 + tl;
        float v = (tap < 5) ? w2[c2 * 80 + c1 * 5 + tap] : 0.f;
        w2b[i] = __float2bfloat16(v);
    } else if (i < 13312) {
        // w3b[c3][kk*32 + c1] = w3[c3*160 + c1*5 + kk]
        int j = i - 3072;
        int c3 = j / 160, rest = j - c3 * 160;
        int kk = rest >> 5, c1 = rest & 31;
        w3b[j] = __float2bfloat16(w3[c3 * 160 + c1 * 5 + kk]);
    } else if (i < 29696) {
        int j = i - 13312;
        winb[j] = __float2bfloat16((j < 8192 ? in1w : in2w)[j & 8191]);
    } else {
        int j = i - 29696;
        owb[j] = __float2bfloat16((j < 4096 ? ow1 : ow2)[j & 4095]);
    }
}

// ---------------- fused conv trunk, 4 blocks per batch (halo recompute), ~35 KB LDS
__global__ __launch_bounds__(256) void conv_trunk(const float* __restrict__ x,
                                                  const float* __restrict__ c1w,
                                                  const float* __restrict__ c1b,
                                                  const __hip_bfloat16* __restrict__ w2b,
                                                  const float* __restrict__ c2b,
                                                  const __hip_bfloat16* __restrict__ w3b,
                                                  const float* __restrict__ c3b,
                                                  __hip_bfloat16* __restrict__ h3b) {
    __shared__ uint4 H1u[1088];   // h1 local rows [0,544): global pos p0+r, 2 units/row
    __shared__ uint4 H2u[1088];   // h2 pooled local rows [0,272): global J = h*256-2+rr, 4 units/row
    float* xs = (float*)H2u;      // alias: raw input staged here during phase 1 only
    int t = threadIdx.x, h = blockIdx.x, b = blockIdx.y;
    int lane = t & 63, w = t >> 6, m = lane & 15, quad = lane >> 4;
    int p0 = h * 512 - 6;         // h1 global base for local row 0
    int gbase = h * 1024 - 14;    // x global base for xs[0]

    // ---- stage x
    const float* xb = x + b * 4096;
    for (int i = t; i < 1080; i += 256) {
        int gx = gbase + i;
        xs[i] = (gx >= 0 && gx < 4096) ? xb[gx] : 0.f;
    }
    // hoist conv2 B-fragments + conv1 weights
    U4 Bf2[3][2];
    {
        const uint4* wsrc = (const uint4*)w2b;
#pragma unroll
        for (int ct = 0; ct < 2; ++ct)
#pragma unroll
            for (int tp = 0; tp < 3; ++tp)
                Bf2[tp][ct].u = wsrc[(ct * 16 + m) * 12 + tp * 4 + quad];
    }
    float bv2[2];
#pragma unroll
    for (int ct = 0; ct < 2; ++ct) bv2[ct] = c2b[ct * 16 + m];
    float wv[80], bv1[16];
#pragma unroll
    for (int i = 0; i < 80; ++i) wv[i] = c1w[i];
#pragma unroll
    for (int i = 0; i < 16; ++i) bv1[i] = c1b[i];
    __syncthreads();

    // ---- phase 1: conv1(k5)+maxpool2+relu -> H1 rows [0,536)
    for (int r = t; r < 536; r += 256) {
        int p = p0 + r;
        union { uint4 q[2]; __hip_bfloat16 hh[16]; } o;
        if (p >= 0 && p < 2048) {
            const float* s = xs + 2 * r;
            float s0 = s[0], s1 = s[1], s2 = s[2], s3 = s[3], s4 = s[4], s5 = s[5];
#pragma unroll
            for (int c = 0; c < 16; ++c) {
                const float* wr = wv + c * 5;
                float v0 = fmaf(wr[0], s0, fmaf(wr[1], s1, fmaf(wr[2], s2, fmaf(wr[3], s3, fmaf(wr[4], s4, bv1[c])))));
                float v1 = fmaf(wr[0], s1, fmaf(wr[1], s2, fmaf(wr[2], s3, fmaf(wr[3], s4, fmaf(wr[4], s5, bv1[c])))));
                o.hh[c] = __float2bfloat16(fmaxf(fmaxf(v0, v1), 0.f));
            }
        } else {
            o.q[0] = (uint4){0, 0, 0, 0};
            o.q[1] = (uint4){0, 0, 0, 0};
        }
        H1u[swz(2 * r)] = o.q[0];
        H1u[swz(2 * r + 1)] = o.q[1];
    }
    __syncthreads();

    // ---- phase 2: conv2(k5)+maxpool2+relu MFMA -> H2 pooled rows [0,264)
    __hip_bfloat16* H2h = (__hip_bfloat16*)H2u;
    for (int g = w; g < 33; g += 4) {
        f32x4 acc[2];
#pragma unroll
        for (int ct = 0; ct < 2; ++ct) acc[ct] = (f32x4){bv2[ct], bv2[ct], bv2[ct], bv2[ct]};
#pragma unroll
        for (int tp = 0; tp < 3; ++tp) {
            int u = 2 * (g * 16 + m + 2 * tp) + quad;
            U4 av; av.u = H1u[swz(u)];
            acc[0] = __builtin_amdgcn_mfma_f32_16x16x32_bf16(av.s8, Bf2[tp][0].s8, acc[0], 0, 0, 0);
            acc[1] = __builtin_amdgcn_mfma_f32_16x16x32_bf16(av.s8, Bf2[tp][1].s8, acc[1], 0, 0, 0);
        }
        int pp = g * 8 + quad * 2;
#pragma unroll
        for (int ct = 0; ct < 2; ++ct) {
            float o0 = fmaxf(fmaxf(acc[ct][0], acc[ct][1]), 0.f);
            float o1 = fmaxf(fmaxf(acc[ct][2], acc[ct][3]), 0.f);
            int ch = ct * 16 + m;
            int u0 = pp * 4 + (ch >> 3);
            H2h[swz(u0) * 8 + (ch & 7)] = __float2bfloat16(o0);
            H2h[swz(u0 + 4) * 8 + (ch & 7)] = __float2bfloat16(o1);
        }
    }
    __syncthreads();
    // zero the out-of-range pooled rows (reference zero-pads h2 for conv3)
    if (h == 0 && t < 8) H2u[swz((t >> 2) * 4 + (t & 3))] = (uint4){0, 0, 0, 0};
    if (h == 3 && t < 8) H2u[swz((258 + (t >> 2)) * 4 + (t & 3))] = (uint4){0, 0, 0, 0};
    __syncthreads();

    // ---- phase 3: conv3(k5)+relu+avgpool(32) MFMA -> h3b (8 windows per block)
    U4 Bf3[5][4];
    {
        const uint4* wsrc = (const uint4*)w3b;
#pragma unroll
        for (int ct = 0; ct < 4; ++ct)
#pragma unroll
            for (int kk = 0; kk < 5; ++kk)
                Bf3[kk][ct].u = wsrc[(ct * 16 + m) * 20 + kk * 4 + quad];
    }
    float bv3[4];
#pragma unroll
    for (int ct = 0; ct < 4; ++ct) bv3[ct] = c3b[ct * 16 + m];

#pragma unroll
    for (int ww = 0; ww < 2; ++ww) {
        int wl = w * 2 + ww;
        float sum[4] = {0.f, 0.f, 0.f, 0.f};
#pragma unroll
        for (int half = 0; half < 2; ++half) {
            int gp = wl * 2 + half;
            f32x4 acc[4];
#pragma unroll
            for (int ct = 0; ct < 4; ++ct) acc[ct] = (f32x4){bv3[ct], bv3[ct], bv3[ct], bv3[ct]};
#pragma unroll
            for (int kk = 0; kk < 5; ++kk) {
                int u = 4 * (gp * 16 + m + kk) + quad;
                U4 av; av.u = H2u[swz(u)];
#pragma unroll
                for (int ct = 0; ct < 4; ++ct)
                    acc[ct] = __builtin_amdgcn_mfma_f32_16x16x32_bf16(av.s8, Bf3[kk][ct].s8, acc[ct], 0, 0, 0);
            }
#pragma unroll
            for (int ct = 0; ct < 4; ++ct) {
                sum[ct] += fmaxf(acc[ct][0], 0.f) + fmaxf(acc[ct][1], 0.f)
                         + fmaxf(acc[ct][2], 0.f) + fmaxf(acc[ct][3], 0.f);
            }
        }
#pragma unroll
        for (int ct = 0; ct < 4; ++ct) {
            float s = sum[ct];
            s += __shfl_xor(s, 16, 64);
            s += __shfl_xor(s, 32, 64);
            sum[ct] = s;
        }
        float sv = (quad == 0) ? sum[0] : (quad == 1) ? sum[1] : (quad == 2) ? sum[2] : sum[3];
        int win = h * 8 + wl;
        h3b[b * 2048 + (quad * 16 + m) * 32 + win] = __float2bfloat16(sv * (1.f / 32.f));
    }
}

// ---------------- MFMA GEMM: C[512,4096] = A[512,2048]bf16 @ lw[4096,2048]fp32^T + lb
// 64x64 tile, grid (64,8)=512 blocks (2/CU); B converted fp32->bf16 inline
__global__ __launch_bounds__(256) void lin_gemm_mfma(const __hip_bfloat16* __restrict__ A,
                                                     const float* __restrict__ Bw,
                                                     const float* __restrict__ bias,
                                                     float* __restrict__ C) {
    __shared__ uint4 A_s[512];
    __shared__ uint4 B_s[512];
    int t = threadIdx.x;
    int col0 = blockIdx.x * 64;
    int row0 = blockIdx.y * 64;
    int w = t >> 6, lane = t & 63;
    int m = lane & 15, quad = lane >> 4;
    int lh = w >> 1, eh = w & 1;

    f32x4 acc[2][2];
#pragma unroll
    for (int li = 0; li < 2; ++li)
#pragma unroll
        for (int ei = 0; ei < 2; ++ei) acc[li][ei] = (f32x4){0.f, 0.f, 0.f, 0.f};

    for (int ki = 0; ki < 32; ++ki) {
        int k0 = ki * 64;
#pragma unroll
        for (int p = 0; p < 2; ++p) {
            int id = p * 256 + t;
            int r = id >> 3, u = id & 7;
            A_s[r * 8 + (u ^ (r & 7))] = *(const uint4*)(A + (row0 + r) * 2048 + k0 + u * 8);
            const float4* s4 = (const float4*)(Bw + (size_t)(col0 + r) * 2048 + k0 + u * 8);
            float4 f0 = s4[0], f1 = s4[1];
            union { uint4 q; __hip_bfloat16 hh[8]; } o;
            o.hh[0] = __float2bfloat16(f0.x); o.hh[1] = __float2bfloat16(f0.y);
            o.hh[2] = __float2bfloat16(f0.z); o.hh[3] = __float2bfloat16(f0.w);
            o.hh[4] = __float2bfloat16(f1.x); o.hh[5] = __float2bfloat16(f1.y);
            o.hh[6] = __float2bfloat16(f1.z); o.hh[7] = __float2bfloat16(f1.w);
            B_s[r * 8 + (u ^ (r & 7))] = o.q;
        }
        __syncthreads();
#pragma unroll
        for (int c = 0; c < 2; ++c) {
            int uu = c * 4 + quad;
            U4 av[2], bv[2];
#pragma unroll
            for (int li = 0; li < 2; ++li) {
                int ra = (lh * 2 + li) * 16 + m;
                av[li].u = A_s[ra * 8 + (uu ^ (ra & 7))];
            }
#pragma unroll
            for (int ei = 0; ei < 2; ++ei) {
                int rb = (eh * 2 + ei) * 16 + m;
                bv[ei].u = B_s[rb * 8 + (uu ^ (rb & 7))];
            }
#pragma unroll
            for (int li = 0; li < 2; ++li)
#pragma unroll
                for (int ei = 0; ei < 2; ++ei)
                    acc[li][ei] = __builtin_amdgcn_mfma_f32_16x16x32_bf16(av[li].s8, bv[ei].s8, acc[li][ei], 0, 0, 0);
        }
        __syncthreads();
    }
#pragma unroll
    for (int li = 0; li < 2; ++li)
#pragma unroll
        for (int ei = 0; ei < 2; ++ei) {
            int col = col0 + (eh * 2 + ei) * 16 + m;
            float bvv = bias[col];
#pragma unroll
            for (int reg = 0; reg < 4; ++reg) {
                int row = row0 + (lh * 2 + li) * 16 + quad * 4 + reg;
                C[row * 4096 + col] = acc[li][ei][reg] + bvv;
            }
        }
}

// ---------------- fused double {layernorm + mamba}, MFMA in/out-proj
struct MambaP {
    const float *lng, *lnb, *cvw, *cvb, *xpw, *dtw, *dtb, *al, *dp;
};

__global__ __launch_bounds__(256) void mamba2_kernel(const float* __restrict__ lin,
                                                     const __hip_bfloat16* __restrict__ winb,
                                                     const __hip_bfloat16* __restrict__ owb,
                                                     MambaP p1, MambaP p2,
                                                     float* __restrict__ out) {
    __shared__ float X[64][68];     // input -> (z after in-proj) -> blk0 output
    __shared__ float XI[64][68];    // xi -> u (in place)
    __shared__ float DTS[64][68];   // softplus(dt) transposed [d][l]
    __shared__ float W12[64][14];   // dt0..3 | (B,C) interleaved pairs at 4+2n
    __shared__ uint4 XBu[512];      // bf16 A-operand: LN-out, then gated y
    int b = blockIdx.x, t = threadIdx.x;
    int lane = t & 63, w = t >> 6, m = lane & 15, quad = lane >> 4;
    int l0 = w * 16;

    {
        const float4* lin4 = (const float4*)(lin + b * 4096);
        for (int i = t; i < 1024; i += 256) {
            float4 v = lin4[i];
            *(float4*)(&X[i >> 4][(i & 15) * 4]) = v;
        }
    }
    __syncthreads();

    for (int blk = 0; blk < 2; ++blk) {
        MambaP P = blk ? p2 : p1;

        // ---- LayerNorm: thread (l = t>>2, q = t&3); output ONLY to bf16 XBu
        {
            int l = t >> 2, q = t & 3;
            float4 xv[4];
            const float4* xr = (const float4*)(&X[l][q * 16]);
#pragma unroll
            for (int j = 0; j < 4; ++j) xv[j] = xr[j];
            float s = 0.f;
#pragma unroll
            for (int j = 0; j < 4; ++j) s += (xv[j].x + xv[j].y) + (xv[j].z + xv[j].w);
            s += __shfl_xor(s, 1, 4);
            s += __shfl_xor(s, 2, 4);
            float mm = s * (1.f / 64.f);
            float v = 0.f;
#pragma unroll
            for (int j = 0; j < 4; ++j) {
                float dx;
                dx = xv[j].x - mm; v = fmaf(dx, dx, v);
                dx = xv[j].y - mm; v = fmaf(dx, dx, v);
                dx = xv[j].z - mm; v = fmaf(dx, dx, v);
                dx = xv[j].w - mm; v = fmaf(dx, dx, v);
            }
            v += __shfl_xor(v, 1, 4);
            v += __shfl_xor(v, 2, 4);
            float rstd = rsqrtf(v * (1.f / 64.f) + 1e-5f);
            const float4* g4 = (const float4*)(P.lng + q * 16);
            const float4* bb4 = (const float4*)(P.lnb + q * 16);
            union { uint4 qq[2]; __hip_bfloat16 hh[16]; } o;
#pragma unroll
            for (int j = 0; j < 4; ++j) {
                float4 g = g4[j], bb = bb4[j];
                o.hh[j * 4 + 0] = __float2bfloat16((xv[j].x - mm) * rstd * g.x + bb.x);
                o.hh[j * 4 + 1] = __float2bfloat16((xv[j].y - mm) * rstd * g.y + bb.y);
                o.hh[j * 4 + 2] = __float2bfloat16((xv[j].z - mm) * rstd * g.z + bb.z);
                o.hh[j * 4 + 3] = __float2bfloat16((xv[j].w - mm) * rstd * g.w + bb.w);
            }
            XBu[idx8(l, q * 2)] = o.qq[0];
            XBu[idx8(l, q * 2 + 1)] = o.qq[1];
        }
        __syncthreads();

        // ---- in-projection MFMA: e<64 -> XI fp32, e>=64 -> z into X
        {
            const uint4* wp = (const uint4*)winb + blk * 1024;
            U4 Bf[8][2];
#pragma unroll
            for (int nt = 0; nt < 8; ++nt)
#pragma unroll
                for (int c = 0; c < 2; ++c)
                    Bf[nt][c].u = wp[(nt * 16 + m) * 8 + c * 4 + quad];
            f32x4 acc[8];
#pragma unroll
            for (int nt = 0; nt < 8; ++nt) acc[nt] = (f32x4){0.f, 0.f, 0.f, 0.f};
#pragma unroll
            for (int c = 0; c < 2; ++c) {
                U4 av; av.u = XBu[idx8(l0 + m, c * 4 + quad)];
#pragma unroll
                for (int nt = 0; nt < 8; ++nt)
                    acc[nt] = __builtin_amdgcn_mfma_f32_16x16x32_bf16(av.s8, Bf[nt][c].s8, acc[nt], 0, 0, 0);
            }
#pragma unroll
            for (int nt = 0; nt < 4; ++nt)
#pragma unroll
                for (int reg = 0; reg < 4; ++reg)
                    XI[l0 + quad * 4 + reg][nt * 16 + m] = acc[nt][reg];
#pragma unroll
            for (int nt = 4; nt < 8; ++nt)
#pragma unroll
                for (int reg = 0; reg < 4; ++reg)
                    X[l0 + quad * 4 + reg][(nt - 4) * 16 + m] = acc[nt][reg];
        }
        __syncthreads();

        // ---- causal depthwise conv(k=2)+silu, in place on XI
        {
            int d = t & 63, lg = t >> 6;
            int lc = lg * 16;
            float cur[16];
            float prev = (lc == 0) ? 0.f : XI[lc - 1][d];
#pragma unroll
            for (int j = 0; j < 16; ++j) cur[j] = XI[lc + j][d];
            __syncthreads();
            float w0 = P.cvw[d * 2], w1 = P.cvw[d * 2 + 1], cb = P.cvb[d];
#pragma unroll
            for (int j = 0; j < 16; ++j) {
                float xp = (j == 0) ? prev : cur[j - 1];
                float v = fmaf(w0, xp, fmaf(w1, cur[j], cb));
                XI[lc + j][d] = v / (1.f + __expf(-v));
            }
        }
        __syncthreads();

        // ---- x_dbl = u @ xpw^T -> W12 (dt 0..3; B,C interleaved at 4+2n / 5+2n)
        {
            int l = t & 63, jg = t >> 6;
            float4 xrow[16];
            const float4* xr = (const float4*)(&XI[l][0]);
#pragma unroll
            for (int k4 = 0; k4 < 16; ++k4) xrow[k4] = xr[k4];
#pragma unroll
            for (int jj = 0; jj < 3; ++jj) {
                int j = jg * 3 + jj;
                const float4* wr = (const float4*)(P.xpw + j * 64);
                float a0 = 0.f, a1 = 0.f, a2 = 0.f, a3 = 0.f;
#pragma unroll
                for (int k4 = 0; k4 < 16; ++k4) {
                    float4 wvv = wr[k4];
                    a0 = fmaf(xrow[k4].x, wvv.x, a0);
                    a1 = fmaf(xrow[k4].y, wvv.y, a1);
                    a2 = fmaf(xrow[k4].z, wvv.z, a2);
                    a3 = fmaf(xrow[k4].w, wvv.w, a3);
                }
                float accv = (a0 + a1) + (a2 + a3);
                int slot = (j < 4) ? j : ((j < 8) ? (4 + (j - 4) * 2) : (5 + (j - 8) * 2));
                W12[l][slot] = accv;
            }
        }
        __syncthreads();

        // ---- softplus(dt) precompute, transposed
        {
            int l = t & 63, dg = t >> 6;
            float d0 = W12[l][0], d1 = W12[l][1], d2 = W12[l][2], d3 = W12[l][3];
#pragma unroll 4
            for (int jj = 0; jj < 16; ++jj) {
                int d = dg * 16 + jj;
                const float4 wvv = *(const float4*)(P.dtw + d * 4);
                float xdt = fmaf(wvv.x, d0, fmaf(wvv.y, d1, fmaf(wvv.z, d2, fmaf(wvv.w, d3, P.dtb[d]))));
                DTS[d][l] = fmaxf(xdt, 0.f) + __logf(1.f + __expf(-fabsf(xdt)));
            }
        }
        __syncthreads();

        // ---- selective scan: thread (d = t>>2, n = t&3); gated y -> bf16 XBu (as YB)
        {
            int d = t >> 2, n = t & 3;
            float Aval = -__expf(P.al[d * 4 + n]);
            float dpv = P.dp[d];
            const float* dtrow = &DTS[d][0];
            ushort* YBh = (ushort*)XBu;
            float h = 0.f;
#pragma unroll 4
            for (int l = 0; l < 64; ++l) {
                float dtv = dtrow[l];
                float dA = __expf(dtv * Aval);
                float uv = XI[l][d];
                float2 bc = *(const float2*)(&W12[l][4 + n * 2]);
                h = fmaf(dA, h, dtv * bc.x * uv);
                float part = h * bc.y;
                part += __shfl_xor(part, 1, 4);
                part += __shfl_xor(part, 2, 4);
                if (n == 0) {
                    float zv = X[l][d];
                    float yv = part + dpv * uv;
                    float gy = yv * (zv / (1.f + __expf(-zv)));
                    BF cv; cv.h = __float2bfloat16(gy);
                    YBh[idx8(l, d >> 3) * 8 + (d & 7)] = cv.us;
                }
            }
        }
        __syncthreads();

        // ---- out-projection MFMA: reads YB (=XBu); blk0 -> X, blk1 -> global
        {
            const uint4* wp = (const uint4*)owb + blk * 512;
            U4 Bf[4][2];
#pragma unroll
            for (int nt = 0; nt < 4; ++nt)
#pragma unroll
                for (int c = 0; c < 2; ++c)
                    Bf[nt][c].u = wp[(nt * 16 + m) * 8 + c * 4 + quad];
            f32x4 acc[4];
#pragma unroll
            for (int nt = 0; nt < 4; ++nt) acc[nt] = (f32x4){0.f, 0.f, 0.f, 0.f};
#pragma unroll
            for (int c = 0; c < 2; ++c) {
                U4 av; av.u = XBu[idx8(l0 + m, c * 4 + quad)];
#pragma unroll
                for (int nt = 0; nt < 4; ++nt)
                    acc[nt] = __builtin_amdgcn_mfma_f32_16x16x32_bf16(av.s8, Bf[nt][c].s8, acc[nt], 0, 0, 0);
            }
            if (blk == 0) {
#pragma unroll
                for (int nt = 0; nt < 4; ++nt)
#pragma unroll
                    for (int reg = 0; reg < 4; ++reg)
                        X[l0 + quad * 4 + reg][nt * 16 + m] = acc[nt][reg];
            } else {
                float* ob = out + b * 4096;
#pragma unroll
                for (int nt = 0; nt < 4; ++nt)
#pragma unroll
                    for (int reg = 0; reg < 4; ++reg)
                        ob[(l0 + quad * 4 + reg) * 64 + nt * 16 + m] = acc[nt][reg];
            }
        }
        __syncthreads();
    }
}

extern "C" void kernel_launch(void* const* d_in, const int* in_sizes, int n_in,
                              void* d_out, int out_size, void* d_ws, size_t ws_size,
                              hipStream_t stream) {
    const float* x   = (const float*)d_in[0];
    const float* c1w = (const float*)d_in[1];
    const float* c1b = (const float*)d_in[2];
    const float* c2w = (const float*)d_in[3];
    const float* c2b = (const float*)d_in[4];
    const float* c3w = (const float*)d_in[5];
    const float* c3b = (const float*)d_in[6];
    const float* lw  = (const float*)d_in[7];
    const float* lb  = (const float*)d_in[8];

    MambaP p1, p2;
    p1.lng = (const float*)d_in[9];  p1.lnb = (const float*)d_in[10];
    p1.cvw = (const float*)d_in[12]; p1.cvb = (const float*)d_in[13];
    p1.xpw = (const float*)d_in[14]; p1.dtw = (const float*)d_in[15];
    p1.dtb = (const float*)d_in[16]; p1.al  = (const float*)d_in[17];
    p1.dp  = (const float*)d_in[18];
    p2.lng = (const float*)d_in[20]; p2.lnb = (const float*)d_in[21];
    p2.cvw = (const float*)d_in[23]; p2.cvb = (const float*)d_in[24];
    p2.xpw = (const float*)d_in[25]; p2.dtw = (const float*)d_in[26];
    p2.dtb = (const float*)d_in[27]; p2.al  = (const float*)d_in[28];
    p2.dp  = (const float*)d_in[29];
    const float* in1w = (const float*)d_in[11];
    const float* in2w = (const float*)d_in[22];
    const float* ow1  = (const float*)d_in[19];
    const float* ow2  = (const float*)d_in[30];

    const size_t MB = 1024 * 1024;
    char* base = (char*)d_ws;
    __hip_bfloat16* h3b  = (__hip_bfloat16*)base;                           // 2 MB
    float* lin           = (float*)(base + 4 * MB);                         // 8 MB
    __hip_bfloat16* w2b  = (__hip_bfloat16*)(base + 16 * MB);               // 6 KB
    __hip_bfloat16* w3b  = (__hip_bfloat16*)(base + 16 * MB + 64 * 1024);   // 20 KB
    __hip_bfloat16* winb = (__hip_bfloat16*)(base + 16 * MB + 256 * 1024);  // 32 KB
    __hip_bfloat16* owb  = (__hip_bfloat16*)(base + 16 * MB + 512 * 1024);  // 16 KB
    float* outp = (float*)d_out;

    prep_w<<<dim3(148), dim3(256), 0, stream>>>(c2w, w2b, c3w, w3b,
                                                in1w, in2w, winb, ow1, ow2, owb);
    conv_trunk<<<dim3(4, NB), dim3(256), 0, stream>>>(x, c1w, c1b, w2b, c2b, w3b, c3b, h3b);
    lin_gemm_mfma<<<dim3(64, 8), dim3(256), 0, stream>>>(h3b, lw, lb, lin);
    mamba2_kernel<<<dim3(NB), dim3(256), 0, stream>>>(lin, winb, owb, p1, p2, outp);
}